// Round 1
// baseline (2767.128 us; speedup 1.0000x reference)
//
#include <hip/hip_runtime.h>
#include <stdint.h>

typedef short short8 __attribute__((ext_vector_type(8)));
typedef float f32x4 __attribute__((ext_vector_type(4)));
typedef float f32x16 __attribute__((ext_vector_type(16)));

#define N_NODES 500
#define HGC 16
#define DH 512
#define T_STEPS 64
#define NB 32
#define F_IN 8
#define DSTEPS 16
#define E_EDGES 16000
#define E_TOT 16500
#define NH 8000          // N*HG
#define G3 1536          // 3*D
#define BT 2048          // B*T
#define KSPLIT 5         // decoder GEMM K-split (500 k-iters / 5 = 100)

__device__ __forceinline__ unsigned short f2bf(float x) {
  unsigned int u = __float_as_uint(x);
  u = (u + 0x7fffu + ((u >> 16) & 1u)) >> 16;
  return (unsigned short)u;
}
__device__ __forceinline__ float bflo(unsigned int w) { return __uint_as_float(w << 16); }
__device__ __forceinline__ float bfhi(unsigned int w) { return __uint_as_float(w & 0xffff0000u); }

__device__ __forceinline__ void gl_lds16(const void* g, void* l) {
  __builtin_amdgcn_global_load_lds((const __attribute__((address_space(1))) void*)g,
                                   (__attribute__((address_space(3))) void*)l, 16, 0, 0);
}

// ---------------- graph prep ----------------
__global__ void k_deg_init(int* deg) {
  int t = blockIdx.x * blockDim.x + threadIdx.x;
  if (t < N_NODES) deg[t] = 1;  // self loop
}

__global__ void k_deg_count(const int* __restrict__ ei, int* deg) {
  int t = blockIdx.x * blockDim.x + threadIdx.x;
  if (t < E_EDGES) atomicAdd(&deg[ei[E_EDGES + t]], 1);
}

__global__ void k_scan(const int* __restrict__ deg, float* dinv, int* rowptr, int* cursor) {
  __shared__ int s[512];
  int t = threadIdx.x;
  int v = (t < N_NODES) ? deg[t] : 0;
  s[t] = v;
  __syncthreads();
  for (int off = 1; off < 512; off <<= 1) {
    int add = (t >= off) ? s[t - off] : 0;
    __syncthreads();
    s[t] += add;
    __syncthreads();
  }
  if (t < N_NODES) {
    int excl = s[t] - v;
    rowptr[t] = excl;
    cursor[t] = excl;
    dinv[t] = rsqrtf((float)v);
  }
  if (t == 0) rowptr[N_NODES] = s[511];
}

__global__ void k_scatter(const int* __restrict__ ei, const float* __restrict__ dinv,
                          int* cursor, int* col, float* nrm) {
  int t = blockIdx.x * blockDim.x + threadIdx.x;
  if (t >= E_TOT) return;
  int s_, d_;
  if (t < E_EDGES) { s_ = ei[t]; d_ = ei[E_EDGES + t]; }
  else { s_ = d_ = t - E_EDGES; }
  int pos = atomicAdd(&cursor[d_], 1);
  col[pos] = s_;
  nrm[pos] = dinv[s_] * dinv[d_];
}

// ---------------- weight conversion ----------------
__global__ void k_f2bf4(const float* __restrict__ src, unsigned short* __restrict__ dst, int n4) {
  int i = blockIdx.x * blockDim.x + threadIdx.x;
  if (i >= n4) return;
  float4 v = ((const float4*)src)[i];
  ushort4 o;
  o.x = f2bf(v.x); o.y = f2bf(v.y); o.z = f2bf(v.z); o.w = f2bf(v.w);
  ((ushort4*)dst)[i] = o;
}

// pack Whh(1536x512) -> wt2[k2][1536], word = bf16(W[r][2k2]) | bf16(W[r][2k2+1])<<16
__global__ void k_pack2(const float* __restrict__ Whh, unsigned int* __restrict__ wt2) {
  int i = blockIdx.x * blockDim.x + threadIdx.x;
  if (i >= 256 * G3) return;
  int k2 = i / G3, r = i - k2 * G3;
  float a = Whh[r * DH + 2 * k2], b = Whh[r * DH + 2 * k2 + 1];
  wt2[i] = (unsigned int)f2bf(a) | ((unsigned int)f2bf(b) << 16);
}

// ---------------- encoder GCN ----------------
__global__ __launch_bounds__(256) void k_gcn_enc(
    const float* __restrict__ x, const float* __restrict__ W, const float* __restrict__ bias,
    const int* __restrict__ rowptr, const int* __restrict__ col, const float* __restrict__ nrm,
    unsigned short* __restrict__ emb) {
  __shared__ float xs[N_NODES * F_IN];
  __shared__ float hW[N_NODES * HGC];
  __shared__ float Ws[F_IN * HGC];
  __shared__ float bl[HGC];
  int g = blockIdx.x, t = threadIdx.x;
  const float* xg = x + (size_t)g * (N_NODES * F_IN);
  for (int i = t; i < N_NODES * F_IN / 4; i += 256) ((float4*)xs)[i] = ((const float4*)xg)[i];
  if (t < F_IN * HGC) Ws[t] = W[t];
  if (t < HGC) bl[t] = bias[t];
  __syncthreads();
  for (int i = t; i < N_NODES * HGC; i += 256) {
    int n = i >> 4, c = i & 15;
    float acc = 0.f;
#pragma unroll
    for (int f = 0; f < F_IN; ++f) acc += xs[n * F_IN + f] * Ws[f * HGC + c];
    hW[i] = acc;
  }
  __syncthreads();
  for (int i = t; i < N_NODES * HGC; i += 256) {
    int n = i >> 4, c = i & 15;
    int e0 = rowptr[n], e1 = rowptr[n + 1];
    float acc = bl[c];
    for (int e = e0; e < e1; ++e) acc += nrm[e] * hW[col[e] * HGC + c];
    emb[(size_t)g * NH + i] = f2bf(fmaxf(acc, 0.f));
  }
}

// ---------------- big encoder GEMM: C(2048x1536) = A(2048x8000) . B(1536x8000)^T, bf16 MFMA ----------------
__global__ __launch_bounds__(256) void k_gemm_enc(
    const unsigned short* __restrict__ A, const unsigned short* __restrict__ Bm,
    float* __restrict__ C) {
  __shared__ unsigned short As[128 * 32];
  __shared__ unsigned short Bs[128 * 32];
  int t = threadIdx.x;
  int m0 = blockIdx.x * 128, n0 = blockIdx.y * 128;
  int wave = t >> 6, lane = t & 63;
  int mh = (wave >> 1) * 64, nh = (wave & 1) * 64;
  int lrow = t >> 2, lslot = t & 3;
  f32x4 acc[4][4];
#pragma unroll
  for (int a = 0; a < 4; ++a)
#pragma unroll
    for (int b = 0; b < 4; ++b) acc[a][b] = (f32x4){0.f, 0.f, 0.f, 0.f};
  const unsigned short* ga0 = A + (size_t)(m0 + lrow) * NH + lslot * 8;
  const unsigned short* ga1 = A + (size_t)(m0 + 64 + lrow) * NH + lslot * 8;
  const unsigned short* gb0 = Bm + (size_t)(n0 + lrow) * NH + lslot * 8;
  const unsigned short* gb1 = Bm + (size_t)(n0 + 64 + lrow) * NH + lslot * 8;
  int rl = lane & 15, ks = lane >> 4;
  for (int kt = 0; kt < 250; ++kt) {
    int k0 = kt * 32;
    gl_lds16(ga0 + k0, &As[t * 8]);
    gl_lds16(ga1 + k0, &As[2048 + t * 8]);
    gl_lds16(gb0 + k0, &Bs[t * 8]);
    gl_lds16(gb1 + k0, &Bs[2048 + t * 8]);
    __syncthreads();
    short8 af[4], bfr[4];
#pragma unroll
    for (int mf = 0; mf < 4; ++mf) af[mf] = *(const short8*)&As[(mh + mf * 16 + rl) * 32 + ks * 8];
#pragma unroll
    for (int nf = 0; nf < 4; ++nf) bfr[nf] = *(const short8*)&Bs[(nh + nf * 16 + rl) * 32 + ks * 8];
#pragma unroll
    for (int mf = 0; mf < 4; ++mf)
#pragma unroll
      for (int nf = 0; nf < 4; ++nf)
        acc[mf][nf] = __builtin_amdgcn_mfma_f32_16x16x32_bf16(af[mf], bfr[nf], acc[mf][nf], 0, 0, 0);
    __syncthreads();
  }
  int rg = lane >> 4;
#pragma unroll
  for (int mf = 0; mf < 4; ++mf)
#pragma unroll
    for (int nf = 0; nf < 4; ++nf) {
      int m = m0 + mh + mf * 16 + rg * 4;
      int n = n0 + nh + nf * 16 + rl;
#pragma unroll
      for (int q = 0; q < 4; ++q) C[(size_t)(m + q) * G3 + n] = acc[mf][nf][q];
    }
}

// ---------------- GRU step (shared enc/dec): gh = h.Whh^T (bf16 packed), fused gates ----------------
__global__ __launch_bounds__(256) void k_gru_step(
    const unsigned int* __restrict__ wt2, const float* __restrict__ gi_base, int gi_bstride,
    int n_parts, int part_stride,
    const float* __restrict__ bih, const float* __restrict__ bhh,
    const float* __restrict__ h_in, float* __restrict__ h_out) {
  __shared__ float h0[DH], h1[DH];
  __shared__ float gh[2][3][64];
  int t = threadIdx.x;
  int bp = blockIdx.x >> 3, c = blockIdx.x & 7;
  int b0 = bp, b1 = bp + 16;
  for (int i = t; i < DH; i += 256) {
    h0[i] = h_in[b0 * DH + i];
    h1[i] = h_in[b1 * DH + i];
  }
  __syncthreads();
  if (t < 192) {
    int gsel = t >> 6, dd = t & 63;
    int row = gsel * DH + c * 64 + dd;
    float a0 = 0.f, a1 = 0.f;
    const unsigned int* wp = wt2 + row;
#pragma unroll 8
    for (int k2 = 0; k2 < 256; ++k2) {
      unsigned int w = wp[(size_t)k2 * G3];
      float wl = bflo(w), wh = bfhi(w);
      float2 p0 = *(const float2*)&h0[2 * k2];
      float2 p1 = *(const float2*)&h1[2 * k2];
      a0 += wl * p0.x + wh * p0.y;
      a1 += wl * p1.x + wh * p1.y;
    }
    gh[0][gsel][dd] = a0;
    gh[1][gsel][dd] = a1;
  }
  __syncthreads();
  if (t < 128) {
    int bs = t >> 6, dd = t & 63, d = c * 64 + dd;
    int b = bs ? b1 : b0;
    const float* gi = gi_base + (size_t)b * gi_bstride;
    float gr = gi[d], gz = gi[DH + d], gn = gi[2 * DH + d];
    for (int p = 1; p < n_parts; ++p) {
      gr += gi[(size_t)p * part_stride + d];
      gz += gi[(size_t)p * part_stride + DH + d];
      gn += gi[(size_t)p * part_stride + 2 * DH + d];
    }
    float hr = gh[bs][0][dd] + bhh[d];
    float hz = gh[bs][1][dd] + bhh[DH + d];
    float hn = gh[bs][2][dd] + bhh[2 * DH + d];
    float ir = gr + bih[d], iz = gz + bih[DH + d], inn = gn + bih[2 * DH + d];
    float r = 1.f / (1.f + __expf(-(ir + hr)));
    float z = 1.f / (1.f + __expf(-(iz + hz)));
    float nn = tanhf(inn + r * hn);
    float hprev = h_in[b * DH + d];
    h_out[b * DH + d] = (1.f - z) * nn + z * hprev;
  }
}

// ---------------- decoder GCN (rank-1 collapse) ----------------
__global__ __launch_bounds__(256) void k_gcn_dec(
    const float* __restrict__ inp, int inp_bstride,
    const float* __restrict__ Wd, const float* __restrict__ bd,
    const int* __restrict__ rowptr, const int* __restrict__ col, const float* __restrict__ nrm,
    unsigned short* __restrict__ eD) {
  __shared__ float is[N_NODES];
  __shared__ float Wl[HGC], bl[HGC];
  int b = blockIdx.x, t = threadIdx.x;
  for (int i = t; i < N_NODES; i += 256) is[i] = inp[(size_t)b * inp_bstride + i];
  if (t < HGC) { Wl[t] = Wd[t]; bl[t] = bd[t]; }
  __syncthreads();
  for (int n = t; n < N_NODES; n += 256) {
    int e0 = rowptr[n], e1 = rowptr[n + 1];
    float acc = 0.f;
    for (int e = e0; e < e1; ++e) acc += nrm[e] * is[col[e]];
    unsigned short* o = eD + (size_t)b * NH + n * HGC;
#pragma unroll
    for (int cc = 0; cc < HGC; ++cc) o[cc] = f2bf(fmaxf(acc * Wl[cc] + bl[cc], 0.f));
  }
}

// ---------------- decoder input GEMM: gi_part[kc] += E8(32x8000) . Wih(1536x8000)^T ----------------
__global__ __launch_bounds__(64) void k_gi_dec(
    const unsigned short* __restrict__ E8, const unsigned short* __restrict__ Wih,
    float* __restrict__ gi_part) {
  int bid = blockIdx.x;              // 0..239
  int nt = bid / KSPLIT, kc = bid - nt * KSPLIT;
  int lane = threadIdx.x;
  int r = lane & 31, kg = lane >> 5;
  f32x16 acc;
#pragma unroll
  for (int q = 0; q < 16; ++q) acc[q] = 0.f;
  const unsigned short* ap = E8 + (size_t)r * NH + kg * 8;
  const unsigned short* bp = Wih + (size_t)(nt * 32 + r) * NH + kg * 8;
  int kbase = kc * 100 * 16;
#pragma unroll 4
  for (int it = 0; it < 100; ++it) {
    int k = kbase + it * 16;
    short8 a = *(const short8*)(ap + k);
    short8 b = *(const short8*)(bp + k);
    acc = __builtin_amdgcn_mfma_f32_32x32x16_bf16(a, b, acc, 0, 0, 0);
  }
  float* outp = gi_part + (size_t)kc * (NB * G3) + nt * 32 + (lane & 31);
#pragma unroll
  for (int q = 0; q < 16; ++q) {
    int brow = (q & 3) + 8 * (q >> 2) + 4 * kg;
    outp[(size_t)brow * G3] = acc[q];
  }
}

// ---------------- fc: out = h . fcW^T + fcb ----------------
__global__ __launch_bounds__(256) void k_fc(
    const float* __restrict__ h, const float* __restrict__ fcW, const float* __restrict__ fcb,
    float* __restrict__ out, int s) {
  int idx = blockIdx.x * 256 + threadIdx.x;
  if (idx >= NB * N_NODES) return;
  int b = idx / N_NODES, n = idx - b * N_NODES;
  const float* hb = h + b * DH;
  const float* wv = fcW + (size_t)n * DH;
  float acc = 0.f;
#pragma unroll 4
  for (int k = 0; k < DH; k += 4) {
    float4 hv = *(const float4*)&hb[k];
    float4 wq = *(const float4*)&wv[k];
    acc += hv.x * wq.x + hv.y * wq.y + hv.z * wq.z + hv.w * wq.w;
  }
  out[(size_t)b * (DSTEPS * N_NODES) + s * N_NODES + n] = acc + fcb[n];
}

extern "C" void kernel_launch(void* const* d_in, const int* in_sizes, int n_in,
                              void* d_out, int out_size, void* d_ws, size_t ws_size,
                              hipStream_t stream) {
  const float* x = (const float*)d_in[0];
  const float* dec0 = (const float*)d_in[1];
  const int* ei = (const int*)d_in[2];
  const float* gWe = (const float*)d_in[3];
  const float* gbe = (const float*)d_in[4];
  const float* gWd = (const float*)d_in[5];
  const float* gbd = (const float*)d_in[6];
  const float* eWih = (const float*)d_in[7];
  const float* eWhh = (const float*)d_in[8];
  const float* ebih = (const float*)d_in[9];
  const float* ebhh = (const float*)d_in[10];
  const float* dWih = (const float*)d_in[11];
  const float* dWhh = (const float*)d_in[12];
  const float* dbih = (const float*)d_in[13];
  const float* dbhh = (const float*)d_in[14];
  const float* fcW = (const float*)d_in[15];
  const float* fcb = (const float*)d_in[16];
  float* out = (float*)d_out;
  (void)in_sizes; (void)n_in; (void)out_size; (void)ws_size;

  char* w = (char*)d_ws;
  size_t off = 0;
  auto alloc = [&](size_t bytes) -> void* {
    void* p = w + off;
    off = (off + bytes + 255) & ~(size_t)255;
    return p;
  };
  int* deg = (int*)alloc(512 * 4);
  float* dinv = (float*)alloc(512 * 4);
  int* rowptr = (int*)alloc(512 * 4);
  int* cursor = (int*)alloc(512 * 4);
  int* colA = (int*)alloc(E_TOT * 4);
  float* nrmA = (float*)alloc(E_TOT * 4);
  unsigned short* emb = (unsigned short*)alloc((size_t)BT * NH * 2);
  unsigned short* wihE = (unsigned short*)alloc((size_t)G3 * NH * 2);
  unsigned short* wihD = (unsigned short*)alloc((size_t)G3 * NH * 2);
  unsigned int* wt2E = (unsigned int*)alloc(256 * G3 * 4);
  unsigned int* wt2D = (unsigned int*)alloc(256 * G3 * 4);
  float* giE = (float*)alloc((size_t)BT * G3 * 4);
  float* giP = (float*)alloc((size_t)KSPLIT * NB * G3 * 4);
  unsigned short* eD = (unsigned short*)alloc((size_t)NB * NH * 2);
  float* hA = (float*)alloc(NB * DH * 4);
  float* hB = (float*)alloc(NB * DH * 4);

  hipMemsetAsync(hA, 0, NB * DH * 4, stream);

  k_deg_init<<<2, 256, 0, stream>>>(deg);
  k_deg_count<<<(E_EDGES + 255) / 256, 256, 0, stream>>>(ei, deg);
  k_scan<<<1, 512, 0, stream>>>(deg, dinv, rowptr, cursor);
  k_scatter<<<(E_TOT + 255) / 256, 256, 0, stream>>>(ei, dinv, cursor, colA, nrmA);

  int n4 = G3 * NH / 4;
  k_f2bf4<<<(n4 + 255) / 256, 256, 0, stream>>>(eWih, wihE, n4);
  k_f2bf4<<<(n4 + 255) / 256, 256, 0, stream>>>(dWih, wihD, n4);
  k_pack2<<<(256 * G3 + 255) / 256, 256, 0, stream>>>(eWhh, wt2E);
  k_pack2<<<(256 * G3 + 255) / 256, 256, 0, stream>>>(dWhh, wt2D);

  k_gcn_enc<<<BT, 256, 0, stream>>>(x, gWe, gbe, rowptr, colA, nrmA, emb);

  dim3 gg(BT / 128, G3 / 128);
  k_gemm_enc<<<gg, 256, 0, stream>>>(emb, wihE, giE);

  float* hin = hA;
  float* hout = hB;
  for (int s = 0; s < T_STEPS; ++s) {
    k_gru_step<<<128, 256, 0, stream>>>(wt2E, giE + (size_t)s * G3, T_STEPS * G3, 1, 0,
                                        ebih, ebhh, hin, hout);
    float* tmp = hin; hin = hout; hout = tmp;
  }
  for (int s = 0; s < DSTEPS; ++s) {
    const float* inp = (s == 0) ? dec0 : (const float*)(out + (size_t)(s - 1) * N_NODES);
    int bstride = (s == 0) ? N_NODES : DSTEPS * N_NODES;
    k_gcn_dec<<<NB, 256, 0, stream>>>(inp, bstride, gWd, gbd, rowptr, colA, nrmA, eD);
    k_gi_dec<<<48 * KSPLIT, 64, 0, stream>>>(eD, wihD, giP);
    k_gru_step<<<128, 256, 0, stream>>>(wt2D, giP, G3, KSPLIT, NB * G3, dbih, dbhh, hin, hout);
    k_fc<<<(NB * N_NODES + 255) / 256, 256, 0, stream>>>(hout, fcW, fcb, out, s);
    float* tmp = hin; hin = hout; hout = tmp;
  }
}

// Round 2
// 2516.502 us; speedup vs baseline: 1.0996x; 1.0996x over previous
//
#include <hip/hip_runtime.h>
#include <stdint.h>

typedef short short8 __attribute__((ext_vector_type(8)));
typedef float f32x4 __attribute__((ext_vector_type(4)));
typedef float f32x16 __attribute__((ext_vector_type(16)));

#define N_NODES 500
#define HGC 16
#define DH 512
#define T_STEPS 64
#define NB 32
#define F_IN 8
#define DSTEPS 16
#define E_EDGES 16000
#define E_TOT 16500
#define NH 8000          // N*HG
#define G3 1536          // 3*D
#define BT 2048          // B*T

__device__ __forceinline__ unsigned short f2bf(float x) {
  unsigned int u = __float_as_uint(x);
  u = (u + 0x7fffu + ((u >> 16) & 1u)) >> 16;
  return (unsigned short)u;
}

__device__ __forceinline__ void gl_lds16(const void* g, void* l) {
  __builtin_amdgcn_global_load_lds((const __attribute__((address_space(1))) void*)g,
                                   (__attribute__((address_space(3))) void*)l, 16, 0, 0);
}

__device__ __forceinline__ float sigm(float x) { return 1.f / (1.f + __expf(-x)); }

// ---------------- graph prep ----------------
__global__ void k_deg_init(int* deg) {
  int t = blockIdx.x * blockDim.x + threadIdx.x;
  if (t < N_NODES) deg[t] = 1;  // self loop
}

__global__ void k_deg_count(const int* __restrict__ ei, int* deg) {
  int t = blockIdx.x * blockDim.x + threadIdx.x;
  if (t < E_EDGES) atomicAdd(&deg[ei[E_EDGES + t]], 1);
}

__global__ void k_scan(const int* __restrict__ deg, float* dinv, int* rowptr, int* cursor) {
  __shared__ int s[512];
  int t = threadIdx.x;
  int v = (t < N_NODES) ? deg[t] : 0;
  s[t] = v;
  __syncthreads();
  for (int off = 1; off < 512; off <<= 1) {
    int add = (t >= off) ? s[t - off] : 0;
    __syncthreads();
    s[t] += add;
    __syncthreads();
  }
  if (t < N_NODES) {
    int excl = s[t] - v;
    rowptr[t] = excl;
    cursor[t] = excl;
    dinv[t] = rsqrtf((float)v);
  }
  if (t == 0) rowptr[N_NODES] = s[511];
}

__global__ void k_scatter(const int* __restrict__ ei, const float* __restrict__ dinv,
                          int* cursor, int* col, float* nrm) {
  int t = blockIdx.x * blockDim.x + threadIdx.x;
  if (t >= E_TOT) return;
  int s_, d_;
  if (t < E_EDGES) { s_ = ei[t]; d_ = ei[E_EDGES + t]; }
  else { s_ = d_ = t - E_EDGES; }
  int pos = atomicAdd(&cursor[d_], 1);
  col[pos] = s_;
  nrm[pos] = dinv[s_] * dinv[d_];
}

// ---------------- f32 -> bf16 bulk convert ----------------
__global__ void k_f2bf4(const float* __restrict__ src, unsigned short* __restrict__ dst, int n4) {
  int i = blockIdx.x * blockDim.x + threadIdx.x;
  if (i >= n4) return;
  float4 v = ((const float4*)src)[i];
  ushort4 o;
  o.x = f2bf(v.x); o.y = f2bf(v.y); o.z = f2bf(v.z); o.w = f2bf(v.w);
  ((ushort4*)dst)[i] = o;
}

// ---------------- x (2048,500,8) f32 -> xT2 (16384, 512) bf16 (zero-padded cols) ----------------
__global__ __launch_bounds__(256) void k_transpose(const float* __restrict__ x,
                                                   unsigned short* __restrict__ xT2) {
  __shared__ float xs[N_NODES * 9];
  int g = blockIdx.x, t = threadIdx.x;
  const float4* xg = (const float4*)(x + (size_t)g * (N_NODES * F_IN));
  for (int i = t; i < N_NODES * 2; i += 256) {
    float4 v = xg[i];
    int n = i >> 1, fh = (i & 1) * 4;
    float* d = &xs[n * 9 + fh];
    d[0] = v.x; d[1] = v.y; d[2] = v.z; d[3] = v.w;
  }
  __syncthreads();
  int f = t >> 5, u = t & 31;
  short8 lo, hi;
#pragma unroll
  for (int j = 0; j < 8; ++j) {
    int n0 = u * 16 + j, n1 = n0 + 8;
    lo[j] = (short)((n0 < N_NODES) ? f2bf(xs[n0 * 9 + f]) : 0);
    hi[j] = (short)((n1 < N_NODES) ? f2bf(xs[n1 * 9 + f]) : 0);
  }
  unsigned short* dst = xT2 + (size_t)(g * 8 + f) * 512 + u * 16;
  *(short8*)dst = lo;
  *(short8*)(dst + 8) = hi;
}

// ---------------- densify Ahat rows (by dst) -> (512, 512) bf16 ----------------
__global__ __launch_bounds__(256) void k_densify(const int* __restrict__ rowptr,
                                                 const int* __restrict__ col,
                                                 const float* __restrict__ nrm,
                                                 unsigned short* __restrict__ AhatD) {
  __shared__ float row[512];
  int n = blockIdx.x, t = threadIdx.x;
  row[t] = 0.f; row[t + 256] = 0.f;
  __syncthreads();
  if (n < N_NODES) {
    int e1 = rowptr[n + 1];
    for (int e = rowptr[n] + t; e < e1; e += 256) atomicAdd(&row[col[e]], nrm[e]);
  }
  __syncthreads();
  AhatD[n * 512 + t] = f2bf(row[t]);
  AhatD[n * 512 + t + 256] = f2bf(row[t + 256]);
}

// ---------------- agg GEMM: C(16384 gf, 512 n) = xT2 . AhatD^T ; fused W(8->16)+relu -> emb ----------------
__global__ __launch_bounds__(256) void k_gemm_agg(const unsigned short* __restrict__ A,
                                                  const unsigned short* __restrict__ B,
                                                  const float* __restrict__ W,
                                                  const float* __restrict__ bias,
                                                  unsigned short* __restrict__ emb) {
  __shared__ float smem[64 * 129];
  __shared__ float Wsm[F_IN * HGC];
  __shared__ float bsm[HGC];
  unsigned short* As = (unsigned short*)smem;
  unsigned short* Bs = As + 4096;
  int t = threadIdx.x;
  if (t < F_IN * HGC) Wsm[t] = W[t];
  if (t < HGC) bsm[t] = bias[t];
  int m0 = blockIdx.x * 128, n0 = blockIdx.y * 128;
  int wave = t >> 6, lane = t & 63;
  int mh = (wave >> 1) * 64, nh = (wave & 1) * 64;
  int lrow = t >> 2, lslot = t & 3;
  f32x4 acc[4][4];
#pragma unroll
  for (int a = 0; a < 4; ++a)
#pragma unroll
    for (int b = 0; b < 4; ++b) acc[a][b] = (f32x4){0.f, 0.f, 0.f, 0.f};
  const unsigned short* ga0 = A + (size_t)(m0 + lrow) * 512 + lslot * 8;
  const unsigned short* ga1 = A + (size_t)(m0 + 64 + lrow) * 512 + lslot * 8;
  const unsigned short* gb0 = B + (size_t)(n0 + lrow) * 512 + lslot * 8;
  const unsigned short* gb1 = B + (size_t)(n0 + 64 + lrow) * 512 + lslot * 8;
  int rl = lane & 15, ks = lane >> 4;
  for (int kt = 0; kt < 16; ++kt) {
    int k0 = kt * 32;
    gl_lds16(ga0 + k0, &As[t * 8]);
    gl_lds16(ga1 + k0, &As[2048 + t * 8]);
    gl_lds16(gb0 + k0, &Bs[t * 8]);
    gl_lds16(gb1 + k0, &Bs[2048 + t * 8]);
    __syncthreads();
    short8 af[4], bfr[4];
#pragma unroll
    for (int mf = 0; mf < 4; ++mf) af[mf] = *(const short8*)&As[(mh + mf * 16 + rl) * 32 + ks * 8];
#pragma unroll
    for (int nf = 0; nf < 4; ++nf) bfr[nf] = *(const short8*)&Bs[(nh + nf * 16 + rl) * 32 + ks * 8];
#pragma unroll
    for (int mf = 0; mf < 4; ++mf)
#pragma unroll
      for (int nf = 0; nf < 4; ++nf)
        acc[mf][nf] = __builtin_amdgcn_mfma_f32_16x16x32_bf16(af[mf], bfr[nf], acc[mf][nf], 0, 0, 0);
    __syncthreads();
  }
  int rg = lane >> 4;
  // epilogue: two half-tiles of 64 gf-rows through LDS (stride 129), apply W+relu, write emb
  for (int p = 0; p < 2; ++p) {
    if ((wave >> 1) == p) {
#pragma unroll
      for (int mf = 0; mf < 4; ++mf)
#pragma unroll
        for (int nf = 0; nf < 4; ++nf)
#pragma unroll
          for (int q = 0; q < 4; ++q)
            smem[(mf * 16 + rg * 4 + q) * 129 + nh + nf * 16 + rl] = acc[mf][nf][q];
    }
    __syncthreads();
    int gl = t >> 5, sub = t & 31;
    int g = blockIdx.x * 16 + p * 8 + gl;
#pragma unroll
    for (int j = 0; j < 4; ++j) {
      int nl = sub + 32 * j, ng = n0 + nl;
      if (ng < N_NODES) {
        float v[8];
#pragma unroll
        for (int f = 0; f < 8; ++f) v[f] = smem[(gl * 8 + f) * 129 + nl];
        short8 o0, o1;
#pragma unroll
        for (int c = 0; c < 8; ++c) {
          float s0 = bsm[c], s1 = bsm[c + 8];
#pragma unroll
          for (int f = 0; f < 8; ++f) {
            s0 += v[f] * Wsm[f * 16 + c];
            s1 += v[f] * Wsm[f * 16 + c + 8];
          }
          o0[c] = (short)f2bf(fmaxf(s0, 0.f));
          o1[c] = (short)f2bf(fmaxf(s1, 0.f));
        }
        unsigned short* dst = emb + (size_t)g * NH + ng * 16;
        *(short8*)dst = o0;
        *(short8*)(dst + 8) = o1;
      }
    }
    __syncthreads();
  }
}

// ---------------- big encoder GEMM: gi(2048x1536) = emb(2048x8000) . Wih(1536x8000)^T ----------------
__global__ __launch_bounds__(256) void k_gemm_enc(
    const unsigned short* __restrict__ A, const unsigned short* __restrict__ Bm,
    float* __restrict__ C) {
  __shared__ unsigned short As[128 * 32];
  __shared__ unsigned short Bs[128 * 32];
  int t = threadIdx.x;
  int m0 = blockIdx.x * 128, n0 = blockIdx.y * 128;
  int wave = t >> 6, lane = t & 63;
  int mh = (wave >> 1) * 64, nh = (wave & 1) * 64;
  int lrow = t >> 2, lslot = t & 3;
  f32x4 acc[4][4];
#pragma unroll
  for (int a = 0; a < 4; ++a)
#pragma unroll
    for (int b = 0; b < 4; ++b) acc[a][b] = (f32x4){0.f, 0.f, 0.f, 0.f};
  const unsigned short* ga0 = A + (size_t)(m0 + lrow) * NH + lslot * 8;
  const unsigned short* ga1 = A + (size_t)(m0 + 64 + lrow) * NH + lslot * 8;
  const unsigned short* gb0 = Bm + (size_t)(n0 + lrow) * NH + lslot * 8;
  const unsigned short* gb1 = Bm + (size_t)(n0 + 64 + lrow) * NH + lslot * 8;
  int rl = lane & 15, ks = lane >> 4;
  for (int kt = 0; kt < 250; ++kt) {
    int k0 = kt * 32;
    gl_lds16(ga0 + k0, &As[t * 8]);
    gl_lds16(ga1 + k0, &As[2048 + t * 8]);
    gl_lds16(gb0 + k0, &Bs[t * 8]);
    gl_lds16(gb1 + k0, &Bs[2048 + t * 8]);
    __syncthreads();
    short8 af[4], bfr[4];
#pragma unroll
    for (int mf = 0; mf < 4; ++mf) af[mf] = *(const short8*)&As[(mh + mf * 16 + rl) * 32 + ks * 8];
#pragma unroll
    for (int nf = 0; nf < 4; ++nf) bfr[nf] = *(const short8*)&Bs[(nh + nf * 16 + rl) * 32 + ks * 8];
#pragma unroll
    for (int mf = 0; mf < 4; ++mf)
#pragma unroll
      for (int nf = 0; nf < 4; ++nf)
        acc[mf][nf] = __builtin_amdgcn_mfma_f32_16x16x32_bf16(af[mf], bfr[nf], acc[mf][nf], 0, 0, 0);
    __syncthreads();
  }
  int rg = lane >> 4;
#pragma unroll
  for (int mf = 0; mf < 4; ++mf)
#pragma unroll
    for (int nf = 0; nf < 4; ++nf) {
      int m = m0 + mh + mf * 16 + rg * 4;
      int n = n0 + nh + nf * 16 + rl;
#pragma unroll
      for (int q = 0; q < 4; ++q) C[(size_t)(m + q) * G3 + n] = acc[mf][nf][q];
    }
}

// ---------------- shared GRU-step device pieces ----------------
// computes gh = h(32x512,bf16 LDS swz) . Whh^T rows [g*512+c0 .. +32) via 32 chained MFMA
__device__ __forceinline__ void gru_core(const unsigned short* __restrict__ whhB,
                                         const unsigned short* hb,  // LDS, swizzled
                                         float* gh,                 // LDS [3][32][32]
                                         int t, int c0) {
  int lane = t & 63, g = t >> 6;
  int b31 = lane & 31, kg = lane >> 5;
  if (g < 3) {
    f32x16 acc;
#pragma unroll
    for (int q = 0; q < 16; ++q) acc[q] = 0.f;
    const unsigned short* brow = whhB + (size_t)(g * 512 + c0 + b31) * 512 + kg * 8;
#pragma unroll 4
    for (int kk = 0; kk < 32; ++kk) {
      int kb = (kk * 32 + kg * 16) ^ ((b31 & 7) << 4);
      short8 a = *(const short8*)((const char*)hb + b31 * 1024 + kb);
      short8 b = *(const short8*)(brow + kk * 16);
      acc = __builtin_amdgcn_mfma_f32_32x32x16_bf16(a, b, acc, 0, 0, 0);
    }
#pragma unroll
    for (int q = 0; q < 16; ++q) {
      int br = (q & 3) + 8 * (q >> 2) + 4 * kg;
      gh[g * 1024 + br * 32 + b31] = acc[q];
    }
  }
}

__device__ __forceinline__ void stage_hb(const unsigned short* __restrict__ src,
                                         unsigned short* hb, int t) {
  int bw = t >> 3, i8 = t & 7;
#pragma unroll
  for (int i = 0; i < 8; ++i) {
    int kb = i8 * 128 + i * 16;
    int sw = kb ^ ((bw & 7) << 4);
    *(short8*)((char*)hb + bw * 1024 + sw) = *(const short8*)((const char*)src + bw * 1024 + kb);
  }
}

__device__ __forceinline__ void gru_gates(const float* gi, const float* gh,
                                          const float* __restrict__ bih,
                                          const float* __restrict__ bhh,
                                          float* __restrict__ hF,
                                          unsigned short* __restrict__ hb_out,
                                          int t, int c0) {
  for (int i = t; i < 1024; i += 256) {
    int b = i >> 5, cc = i & 31, d = c0 + cc;
    float gr = gi[i] + bih[d];
    float gz = gi[1024 + i] + bih[512 + d];
    float gn = gi[2048 + i] + bih[1024 + d];
    float hr = gh[b * 32 + cc] + bhh[d];
    float hz = gh[1024 + b * 32 + cc] + bhh[512 + d];
    float hn = gh[2048 + b * 32 + cc] + bhh[1024 + d];
    float r = sigm(gr + hr), z = sigm(gz + hz);
    float nn = tanhf(gn + r * hn);
    float hp = hF[b * 512 + d];
    float hnew = (1.f - z) * nn + z * hp;
    hF[b * 512 + d] = hnew;
    hb_out[b * 512 + d] = f2bf(hnew);
  }
}

// ---------------- persistent encoder scan: 16 blocks, 64 steps, grid barrier ----------------
__global__ __launch_bounds__(256) void k_enc_scan(
    const unsigned short* __restrict__ whhB, const float* __restrict__ giE,
    const float* __restrict__ bih, const float* __restrict__ bhh,
    float* hF, unsigned short* hb16, unsigned* bar) {
  __shared__ unsigned short hb[32 * 512];
  __shared__ float gh[3 * 32 * 32];
  __shared__ float gi[3 * 32 * 32];
  int t = threadIdx.x;
  int c0 = blockIdx.x * 32;
  for (int s = 0; s < T_STEPS; ++s) {
    stage_hb(hb16, hb, t);
    for (int i = t; i < 3072; i += 256) {
      int gg = i >> 10, r = i & 1023, bb = r >> 5, cc = r & 31;
      gi[i] = giE[(size_t)(bb * T_STEPS + s) * G3 + gg * 512 + c0 + cc];
    }
    __syncthreads();
    gru_core(whhB, hb, gh, t, c0);
    __syncthreads();
    gru_gates(gi, gh, bih, bhh, hF, hb16, t, c0);
    // grid barrier
    __syncthreads();
    if (t == 0) {
      __threadfence();
      unsigned old = __hip_atomic_fetch_add(&bar[0], 1u, __ATOMIC_ACQ_REL, __HIP_MEMORY_SCOPE_AGENT);
      if (old == 15u) {
        __hip_atomic_store(&bar[0], 0u, __ATOMIC_RELAXED, __HIP_MEMORY_SCOPE_AGENT);
        __hip_atomic_fetch_add(&bar[1], 1u, __ATOMIC_ACQ_REL, __HIP_MEMORY_SCOPE_AGENT);
      } else {
        while (__hip_atomic_load(&bar[1], __ATOMIC_ACQUIRE, __HIP_MEMORY_SCOPE_AGENT) < (unsigned)(s + 1)) {
          __builtin_amdgcn_s_sleep(1);
        }
      }
    }
    __syncthreads();
  }
}

// ---------------- decoder GRU step (one launch per step; 16 blocks) ----------------
__global__ __launch_bounds__(256) void k_gru_dec(
    const unsigned short* __restrict__ whhB, const float* __restrict__ parts,
    const float* __restrict__ bih, const float* __restrict__ bhh,
    float* hF, const unsigned short* __restrict__ hb_in, unsigned short* __restrict__ hb_out) {
  __shared__ unsigned short hb[32 * 512];
  __shared__ float gh[3 * 32 * 32];
  __shared__ float gi[3 * 32 * 32];
  int t = threadIdx.x;
  int c0 = blockIdx.x * 32;
  stage_hb(hb_in, hb, t);
  for (int i = t; i < 3072; i += 256) {
    int gg = i >> 10, r = i & 1023, bb = r >> 5, cc = r & 31;
    int d = gg * 512 + c0 + cc;
    float a = 0.f;
#pragma unroll 4
    for (int kc = 0; kc < 20; ++kc) a += parts[(size_t)kc * (NB * G3) + bb * G3 + d];
    gi[i] = a;
  }
  __syncthreads();
  gru_core(whhB, hb, gh, t, c0);
  __syncthreads();
  gru_gates(gi, gh, bih, bhh, hF, hb_out, t, c0);
}

// ---------------- decoder gi GEMM: parts[kc] = E8(32x8000,on-the-fly) . Wih^T ----------------
__global__ __launch_bounds__(256) void k_dec_gemm(
    const unsigned short* __restrict__ wihD, const float* __restrict__ sbuf,
    const float* __restrict__ Wd, const float* __restrict__ bd,
    float* __restrict__ parts) {
  __shared__ float s_lds[32 * 26];
  int t = threadIdx.x;
  int ntile = blockIdx.x, kc = blockIdx.y;  // (12, 20)
  for (int i = t; i < 800; i += 256) {
    int b = i / 25, nn = i - b * 25;
    s_lds[b * 26 + nn] = sbuf[b * N_NODES + kc * 25 + nn];
  }
  int lane = t & 63, w = t >> 6;
  int b31 = lane & 31, kg = lane >> 5;
  float wd8[8], bd8[8];
#pragma unroll
  for (int j = 0; j < 8; ++j) { wd8[j] = Wd[kg * 8 + j]; bd8[j] = bd[kg * 8 + j]; }
  __syncthreads();
  f32x16 acc;
#pragma unroll
  for (int q = 0; q < 16; ++q) acc[q] = 0.f;
  const unsigned short* brow = wihD + (size_t)(ntile * 128 + w * 32 + b31) * NH + kc * 400 + kg * 8;
  for (int kk = 0; kk < 25; ++kk) {
    float sv = s_lds[b31 * 26 + kk];
    short8 av;
#pragma unroll
    for (int j = 0; j < 8; ++j) av[j] = (short)f2bf(fmaxf(sv * wd8[j] + bd8[j], 0.f));
    short8 bv = *(const short8*)(brow + kk * 16);
    acc = __builtin_amdgcn_mfma_f32_32x32x16_bf16(av, bv, acc, 0, 0, 0);
  }
  int colo = ntile * 128 + w * 32 + b31;
#pragma unroll
  for (int q = 0; q < 16; ++q) {
    int br = (q & 3) + 8 * (q >> 2) + 4 * kg;
    parts[(size_t)kc * (NB * G3) + br * G3 + colo] = acc[q];
  }
}

// ---------------- fc + out-aggregation fused (per-b block) ----------------
__global__ __launch_bounds__(256) void k_fc_agg(
    const float* __restrict__ hF, const float* __restrict__ fcW, const float* __restrict__ fcb,
    const int* __restrict__ rowptr, const int* __restrict__ col, const float* __restrict__ nrm,
    float* __restrict__ out, float* __restrict__ sbuf, int s) {
  __shared__ float hrow[512];
  __shared__ float orow[N_NODES];
  int b = blockIdx.x, t = threadIdx.x;
  hrow[t] = hF[b * 512 + t];
  hrow[t + 256] = hF[b * 512 + t + 256];
  __syncthreads();
  for (int n = t; n < N_NODES; n += 256) {
    const float4* wr = (const float4*)(fcW + (size_t)n * DH);
    float a = 0.f;
#pragma unroll 4
    for (int k = 0; k < 128; ++k) {
      float4 wv = wr[k];
      const float4 hv = *(const float4*)&hrow[k * 4];
      a += wv.x * hv.x + wv.y * hv.y + wv.z * hv.z + wv.w * hv.w;
    }
    float o = a + fcb[n];
    orow[n] = o;
    out[(size_t)b * (DSTEPS * N_NODES) + s * N_NODES + n] = o;
  }
  __syncthreads();
  for (int n = t; n < N_NODES; n += 256) {
    int e1 = rowptr[n + 1];
    float a = 0.f;
    for (int e = rowptr[n]; e < e1; ++e) a += nrm[e] * orow[col[e]];
    sbuf[b * N_NODES + n] = a;
  }
}

// ---------------- initial decoder aggregation from decoder_initial_input ----------------
__global__ __launch_bounds__(256) void k_agg0(
    const float* __restrict__ dec0, const int* __restrict__ rowptr,
    const int* __restrict__ col, const float* __restrict__ nrm, float* __restrict__ sbuf) {
  __shared__ float irow[N_NODES];
  int b = blockIdx.x, t = threadIdx.x;
  for (int n = t; n < N_NODES; n += 256) irow[n] = dec0[b * N_NODES + n];
  __syncthreads();
  for (int n = t; n < N_NODES; n += 256) {
    int e1 = rowptr[n + 1];
    float a = 0.f;
    for (int e = rowptr[n]; e < e1; ++e) a += nrm[e] * irow[col[e]];
    sbuf[b * N_NODES + n] = a;
  }
}

extern "C" void kernel_launch(void* const* d_in, const int* in_sizes, int n_in,
                              void* d_out, int out_size, void* d_ws, size_t ws_size,
                              hipStream_t stream) {
  const float* x = (const float*)d_in[0];
  const float* dec0 = (const float*)d_in[1];
  const int* ei = (const int*)d_in[2];
  const float* gWe = (const float*)d_in[3];
  const float* gbe = (const float*)d_in[4];
  const float* gWd = (const float*)d_in[5];
  const float* gbd = (const float*)d_in[6];
  const float* eWih = (const float*)d_in[7];
  const float* eWhh = (const float*)d_in[8];
  const float* ebih = (const float*)d_in[9];
  const float* ebhh = (const float*)d_in[10];
  const float* dWih = (const float*)d_in[11];
  const float* dWhh = (const float*)d_in[12];
  const float* dbih = (const float*)d_in[13];
  const float* dbhh = (const float*)d_in[14];
  const float* fcW = (const float*)d_in[15];
  const float* fcb = (const float*)d_in[16];
  float* out = (float*)d_out;
  (void)in_sizes; (void)n_in; (void)out_size; (void)ws_size;

  char* w = (char*)d_ws;
  size_t off = 0;
  auto alloc = [&](size_t bytes) -> void* {
    void* p = w + off;
    off = (off + bytes + 255) & ~(size_t)255;
    return p;
  };
  int* deg = (int*)alloc(512 * 4);
  float* dinv = (float*)alloc(512 * 4);
  int* rowptr = (int*)alloc(512 * 4);
  int* cursor = (int*)alloc(512 * 4);
  int* colA = (int*)alloc(E_TOT * 4);
  float* nrmA = (float*)alloc(E_TOT * 4);
  unsigned short* whhE = (unsigned short*)alloc((size_t)G3 * DH * 2);
  unsigned short* whhD = (unsigned short*)alloc((size_t)G3 * DH * 2);
  unsigned short* AhatD = (unsigned short*)alloc(512 * 512 * 2);
  float* hF = (float*)alloc(NB * DH * 4);                 // |
  unsigned short* hbX = (unsigned short*)alloc(NB * DH * 2);  // | contiguous: one memset
  unsigned* bar = (unsigned*)alloc(256);                  // |
  unsigned short* hbY = (unsigned short*)alloc(NB * DH * 2);
  float* sbuf = (float*)alloc((size_t)NB * N_NODES * 4);
  unsigned short* emb = (unsigned short*)alloc((size_t)BT * NH * 2);
  char* wihE_parts = (char*)alloc((size_t)G3 * NH * 2);   // wihE, later parts
  unsigned short* wihE = (unsigned short*)wihE_parts;
  float* parts = (float*)wihE_parts;
  unsigned short* wihD = (unsigned short*)alloc((size_t)G3 * NH * 2);
  char* xT2_giE = (char*)alloc((size_t)16384 * 512 * 2);  // xT2, later giE
  unsigned short* xT2 = (unsigned short*)xT2_giE;
  float* giE = (float*)xT2_giE;

  // zero h state + barrier (contiguous region)
  hipMemsetAsync(hF, 0, NB * DH * 4 + NB * DH * 2 + 256 + 512 /*padding slack*/, stream);

  k_deg_init<<<2, 256, 0, stream>>>(deg);
  k_deg_count<<<(E_EDGES + 255) / 256, 256, 0, stream>>>(ei, deg);
  k_scan<<<1, 512, 0, stream>>>(deg, dinv, rowptr, cursor);
  k_scatter<<<(E_TOT + 255) / 256, 256, 0, stream>>>(ei, dinv, cursor, colA, nrmA);

  int n4w = G3 * NH / 4;
  int n4h = G3 * DH / 4;
  k_f2bf4<<<(n4w + 255) / 256, 256, 0, stream>>>(eWih, wihE, n4w);
  k_f2bf4<<<(n4w + 255) / 256, 256, 0, stream>>>(dWih, wihD, n4w);
  k_f2bf4<<<(n4h + 255) / 256, 256, 0, stream>>>(eWhh, whhE, n4h);
  k_f2bf4<<<(n4h + 255) / 256, 256, 0, stream>>>(dWhh, whhD, n4h);

  k_transpose<<<BT, 256, 0, stream>>>(x, xT2);
  k_densify<<<512, 256, 0, stream>>>(rowptr, colA, nrmA, AhatD);
  k_gemm_agg<<<dim3(128, 4), 256, 0, stream>>>(xT2, AhatD, gWe, gbe, emb);

  k_gemm_enc<<<dim3(BT / 128, G3 / 128), 256, 0, stream>>>(emb, wihE, giE);

  k_enc_scan<<<16, 256, 0, stream>>>(whhE, giE, ebih, ebhh, hF, hbX, bar);

  k_agg0<<<NB, 256, 0, stream>>>(dec0, rowptr, colA, nrmA, sbuf);

  for (int s = 0; s < DSTEPS; ++s) {
    const unsigned short* hbin = (s & 1) ? hbY : hbX;
    unsigned short* hbout = (s & 1) ? hbX : hbY;
    k_dec_gemm<<<dim3(12, 20), 256, 0, stream>>>(wihD, sbuf, gWd, gbd, parts);
    k_gru_dec<<<16, 256, 0, stream>>>(whhD, parts, dbih, dbhh, hF, hbin, hbout);
    k_fc_agg<<<NB, 256, 0, stream>>>(hF, fcW, fcb, rowptr, colA, nrmA, out, sbuf, s);
  }
}

// Round 5
// 2079.924 us; speedup vs baseline: 1.3304x; 1.2099x over previous
//
#include <hip/hip_runtime.h>
#include <stdint.h>

typedef short short8 __attribute__((ext_vector_type(8)));
typedef float f32x4 __attribute__((ext_vector_type(4)));
typedef float f32x16 __attribute__((ext_vector_type(16)));

#define N_NODES 500
#define HGC 16
#define DH 512
#define T_STEPS 64
#define NB 32
#define F_IN 8
#define DSTEPS 16
#define E_EDGES 16000
#define E_TOT 16500
#define NH 8000          // N*HG
#define G3 1536          // 3*D
#define BT 2048          // B*T

__device__ __forceinline__ unsigned short f2bf(float x) {
  unsigned int u = __float_as_uint(x);
  u = (u + 0x7fffu + ((u >> 16) & 1u)) >> 16;
  return (unsigned short)u;
}

__device__ __forceinline__ void gl_lds16(const void* g, void* l) {
  __builtin_amdgcn_global_load_lds((const __attribute__((address_space(1))) void*)g,
                                   (__attribute__((address_space(3))) void*)l, 16, 0, 0);
}

__device__ __forceinline__ float sigm(float x) { return 1.f / (1.f + __expf(-x)); }

// ---------------- graph prep ----------------
__global__ void k_deg_init(int* deg) {
  int t = blockIdx.x * blockDim.x + threadIdx.x;
  if (t < N_NODES) deg[t] = 1;  // self loop
}

__global__ void k_deg_count(const int* __restrict__ ei, int* deg) {
  int t = blockIdx.x * blockDim.x + threadIdx.x;
  if (t < E_EDGES) atomicAdd(&deg[ei[E_EDGES + t]], 1);
}

__global__ void k_scan(const int* __restrict__ deg, float* dinv, int* rowptr, int* cursor) {
  __shared__ int s[512];
  int t = threadIdx.x;
  int v = (t < N_NODES) ? deg[t] : 0;
  s[t] = v;
  __syncthreads();
  for (int off = 1; off < 512; off <<= 1) {
    int add = (t >= off) ? s[t - off] : 0;
    __syncthreads();
    s[t] += add;
    __syncthreads();
  }
  if (t < N_NODES) {
    int excl = s[t] - v;
    rowptr[t] = excl;
    cursor[t] = excl;
    dinv[t] = rsqrtf((float)v);
  }
  if (t == 0) rowptr[N_NODES] = s[511];
}

__global__ void k_scatter(const int* __restrict__ ei, const float* __restrict__ dinv,
                          int* cursor, int* col, float* nrm) {
  int t = blockIdx.x * blockDim.x + threadIdx.x;
  if (t >= E_TOT) return;
  int s_, d_;
  if (t < E_EDGES) { s_ = ei[t]; d_ = ei[E_EDGES + t]; }
  else { s_ = d_ = t - E_EDGES; }
  int pos = atomicAdd(&cursor[d_], 1);
  col[pos] = s_;
  nrm[pos] = dinv[s_] * dinv[d_];
}

// ---------------- f32 -> bf16 bulk convert ----------------
__global__ void k_f2bf4(const float* __restrict__ src, unsigned short* __restrict__ dst, int n4) {
  int i = blockIdx.x * blockDim.x + threadIdx.x;
  if (i >= n4) return;
  float4 v = ((const float4*)src)[i];
  ushort4 o;
  o.x = f2bf(v.x); o.y = f2bf(v.y); o.z = f2bf(v.z); o.w = f2bf(v.w);
  ((ushort4*)dst)[i] = o;
}

// ---------------- x (2048,500,8) f32 -> xT2 (16384, 512) bf16 (zero-padded cols) ----------------
__global__ __launch_bounds__(256) void k_transpose(const float* __restrict__ x,
                                                   unsigned short* __restrict__ xT2) {
  __shared__ float xs[N_NODES * 9];
  int g = blockIdx.x, t = threadIdx.x;
  const float4* xg = (const float4*)(x + (size_t)g * (N_NODES * F_IN));
  for (int i = t; i < N_NODES * 2; i += 256) {
    float4 v = xg[i];
    int n = i >> 1, fh = (i & 1) * 4;
    float* d = &xs[n * 9 + fh];
    d[0] = v.x; d[1] = v.y; d[2] = v.z; d[3] = v.w;
  }
  __syncthreads();
  int f = t >> 5, u = t & 31;
  short8 lo, hi;
#pragma unroll
  for (int j = 0; j < 8; ++j) {
    int n0 = u * 16 + j, n1 = n0 + 8;
    lo[j] = (short)((n0 < N_NODES) ? f2bf(xs[n0 * 9 + f]) : 0);
    hi[j] = (short)((n1 < N_NODES) ? f2bf(xs[n1 * 9 + f]) : 0);
  }
  unsigned short* dst = xT2 + (size_t)(g * 8 + f) * 512 + u * 16;
  *(short8*)dst = lo;
  *(short8*)(dst + 8) = hi;
}

// ---------------- densify Ahat rows (by dst) -> (512, 512) bf16 ----------------
__global__ __launch_bounds__(256) void k_densify(const int* __restrict__ rowptr,
                                                 const int* __restrict__ col,
                                                 const float* __restrict__ nrm,
                                                 unsigned short* __restrict__ AhatD) {
  __shared__ float row[512];
  int n = blockIdx.x, t = threadIdx.x;
  row[t] = 0.f; row[t + 256] = 0.f;
  __syncthreads();
  if (n < N_NODES) {
    int e1 = rowptr[n + 1];
    for (int e = rowptr[n] + t; e < e1; e += 256) atomicAdd(&row[col[e]], nrm[e]);
  }
  __syncthreads();
  AhatD[n * 512 + t] = f2bf(row[t]);
  AhatD[n * 512 + t + 256] = f2bf(row[t + 256]);
}

// ---------------- agg GEMM: C(16384 gf, 512 n) = xT2 . AhatD^T ; fused W(8->16)+relu -> emb ----------------
__global__ __launch_bounds__(256) void k_gemm_agg(const unsigned short* __restrict__ A,
                                                  const unsigned short* __restrict__ B,
                                                  const float* __restrict__ W,
                                                  const float* __restrict__ bias,
                                                  unsigned short* __restrict__ emb) {
  __shared__ float smem[64 * 129];
  __shared__ float Wsm[F_IN * HGC];
  __shared__ float bsm[HGC];
  unsigned short* As = (unsigned short*)smem;
  unsigned short* Bs = As + 4096;
  int t = threadIdx.x;
  if (t < F_IN * HGC) Wsm[t] = W[t];
  if (t < HGC) bsm[t] = bias[t];
  int m0 = blockIdx.x * 128, n0 = blockIdx.y * 128;
  int wave = t >> 6, lane = t & 63;
  int mh = (wave >> 1) * 64, nh = (wave & 1) * 64;
  int lrow = t >> 2, lslot = t & 3;
  f32x4 acc[4][4];
#pragma unroll
  for (int a = 0; a < 4; ++a)
#pragma unroll
    for (int b = 0; b < 4; ++b) acc[a][b] = (f32x4){0.f, 0.f, 0.f, 0.f};
  const unsigned short* ga0 = A + (size_t)(m0 + lrow) * 512 + lslot * 8;
  const unsigned short* ga1 = A + (size_t)(m0 + 64 + lrow) * 512 + lslot * 8;
  const unsigned short* gb0 = B + (size_t)(n0 + lrow) * 512 + lslot * 8;
  const unsigned short* gb1 = B + (size_t)(n0 + 64 + lrow) * 512 + lslot * 8;
  int rl = lane & 15, ks = lane >> 4;
  for (int kt = 0; kt < 16; ++kt) {
    int k0 = kt * 32;
    gl_lds16(ga0 + k0, &As[t * 8]);
    gl_lds16(ga1 + k0, &As[2048 + t * 8]);
    gl_lds16(gb0 + k0, &Bs[t * 8]);
    gl_lds16(gb1 + k0, &Bs[2048 + t * 8]);
    __syncthreads();
    short8 af[4], bfr[4];
#pragma unroll
    for (int mf = 0; mf < 4; ++mf) af[mf] = *(const short8*)&As[(mh + mf * 16 + rl) * 32 + ks * 8];
#pragma unroll
    for (int nf = 0; nf < 4; ++nf) bfr[nf] = *(const short8*)&Bs[(nh + nf * 16 + rl) * 32 + ks * 8];
#pragma unroll
    for (int mf = 0; mf < 4; ++mf)
#pragma unroll
      for (int nf = 0; nf < 4; ++nf)
        acc[mf][nf] = __builtin_amdgcn_mfma_f32_16x16x32_bf16(af[mf], bfr[nf], acc[mf][nf], 0, 0, 0);
    __syncthreads();
  }
  int rg = lane >> 4;
  for (int p = 0; p < 2; ++p) {
    if ((wave >> 1) == p) {
#pragma unroll
      for (int mf = 0; mf < 4; ++mf)
#pragma unroll
        for (int nf = 0; nf < 4; ++nf)
#pragma unroll
          for (int q = 0; q < 4; ++q)
            smem[(mf * 16 + rg * 4 + q) * 129 + nh + nf * 16 + rl] = acc[mf][nf][q];
    }
    __syncthreads();
    int gl = t >> 5, sub = t & 31;
    int g = blockIdx.x * 16 + p * 8 + gl;
#pragma unroll
    for (int j = 0; j < 4; ++j) {
      int nl = sub + 32 * j, ng = n0 + nl;
      if (ng < N_NODES) {
        float v[8];
#pragma unroll
        for (int f = 0; f < 8; ++f) v[f] = smem[(gl * 8 + f) * 129 + nl];
        short8 o0, o1;
#pragma unroll
        for (int c = 0; c < 8; ++c) {
          float s0 = bsm[c], s1 = bsm[c + 8];
#pragma unroll
          for (int f = 0; f < 8; ++f) {
            s0 += v[f] * Wsm[f * 16 + c];
            s1 += v[f] * Wsm[f * 16 + c + 8];
          }
          o0[c] = (short)f2bf(fmaxf(s0, 0.f));
          o1[c] = (short)f2bf(fmaxf(s1, 0.f));
        }
        unsigned short* dst = emb + (size_t)g * NH + ng * 16;
        *(short8*)dst = o0;
        *(short8*)(dst + 8) = o1;
      }
    }
    __syncthreads();
  }
}

// ---------------- big encoder GEMM: gi(2048x1536) = emb(2048x8000) . Wih(1536x8000)^T ----------------
__global__ __launch_bounds__(256) void k_gemm_enc(
    const unsigned short* __restrict__ A, const unsigned short* __restrict__ Bm,
    float* __restrict__ C) {
  __shared__ unsigned short As[128 * 32];
  __shared__ unsigned short Bs[128 * 32];
  int t = threadIdx.x;
  int m0 = blockIdx.x * 128, n0 = blockIdx.y * 128;
  int wave = t >> 6, lane = t & 63;
  int mh = (wave >> 1) * 64, nh = (wave & 1) * 64;
  int lrow = t >> 2, lslot = t & 3;
  f32x4 acc[4][4];
#pragma unroll
  for (int a = 0; a < 4; ++a)
#pragma unroll
    for (int b = 0; b < 4; ++b) acc[a][b] = (f32x4){0.f, 0.f, 0.f, 0.f};
  const unsigned short* ga0 = A + (size_t)(m0 + lrow) * NH + lslot * 8;
  const unsigned short* ga1 = A + (size_t)(m0 + 64 + lrow) * NH + lslot * 8;
  const unsigned short* gb0 = Bm + (size_t)(n0 + lrow) * NH + lslot * 8;
  const unsigned short* gb1 = Bm + (size_t)(n0 + 64 + lrow) * NH + lslot * 8;
  int rl = lane & 15, ks = lane >> 4;
  for (int kt = 0; kt < 250; ++kt) {
    int k0 = kt * 32;
    gl_lds16(ga0 + k0, &As[t * 8]);
    gl_lds16(ga1 + k0, &As[2048 + t * 8]);
    gl_lds16(gb0 + k0, &Bs[t * 8]);
    gl_lds16(gb1 + k0, &Bs[2048 + t * 8]);
    __syncthreads();
    short8 af[4], bfr[4];
#pragma unroll
    for (int mf = 0; mf < 4; ++mf) af[mf] = *(const short8*)&As[(mh + mf * 16 + rl) * 32 + ks * 8];
#pragma unroll
    for (int nf = 0; nf < 4; ++nf) bfr[nf] = *(const short8*)&Bs[(nh + nf * 16 + rl) * 32 + ks * 8];
#pragma unroll
    for (int mf = 0; mf < 4; ++mf)
#pragma unroll
      for (int nf = 0; nf < 4; ++nf)
        acc[mf][nf] = __builtin_amdgcn_mfma_f32_16x16x32_bf16(af[mf], bfr[nf], acc[mf][nf], 0, 0, 0);
    __syncthreads();
  }
  int rg = lane >> 4;
#pragma unroll
  for (int mf = 0; mf < 4; ++mf)
#pragma unroll
    for (int nf = 0; nf < 4; ++nf) {
      int m = m0 + mh + mf * 16 + rg * 4;
      int n = n0 + nh + nf * 16 + rl;
#pragma unroll
      for (int q = 0; q < 4; ++q) C[(size_t)(m + q) * G3 + n] = acc[mf][nf][q];
    }
}

// ---------------- shared GRU helpers ----------------
// stage h (32x512 bf16) from global into LDS with (row&15)<<4 XOR swizzle
__device__ __forceinline__ void stage_hb(const unsigned short* __restrict__ src,
                                         unsigned short* hb, int t) {
  int bw = t >> 3, i8 = t & 7;
  short8 v[8];
#pragma unroll
  for (int i = 0; i < 8; ++i)
    v[i] = *(const short8*)((const char*)src + bw * 1024 + i8 * 128 + i * 16);
#pragma unroll
  for (int i = 0; i < 8; ++i) {
    int kb = i8 * 128 + i * 16;
    *(short8*)((char*)hb + bw * 1024 + (kb ^ ((bw & 15) << 4))) = v[i];
  }
}

// decoder: gh = h(32x512 LDS swz) . Whh^T (B from global)
__device__ __forceinline__ void gru_core_g(const unsigned short* __restrict__ whhB,
                                           const unsigned short* hb, float* gh,
                                           int t, int c0) {
  int lane = t & 63, g = t >> 6;
  int b31 = lane & 31, kg = lane >> 5;
  if (g < 3) {
    f32x16 acc;
#pragma unroll
    for (int q = 0; q < 16; ++q) acc[q] = 0.f;
    const unsigned short* brow = whhB + (size_t)(g * 512 + c0 + b31) * 512 + kg * 8;
    int asw = (b31 & 15) << 4;
#pragma unroll 4
    for (int kk = 0; kk < 32; ++kk) {
      int kb = (kk * 32 + kg * 16) ^ asw;
      short8 a = *(const short8*)((const char*)hb + b31 * 1024 + kb);
      short8 b = *(const short8*)(brow + kk * 16);
      acc = __builtin_amdgcn_mfma_f32_32x32x16_bf16(a, b, acc, 0, 0, 0);
    }
#pragma unroll
    for (int q = 0; q < 16; ++q) {
      int br = (q & 3) + 8 * (q >> 2) + 4 * kg;
      gh[g * 1024 + br * 32 + b31] = acc[q];
    }
  }
}

// decoder gates (reads gi LDS, hF global prev-h; writes hF + bf16 h)
__device__ __forceinline__ void gru_gates(const float* gi, const float* gh,
                                          const float* __restrict__ bih,
                                          const float* __restrict__ bhh,
                                          float* __restrict__ hF,
                                          unsigned short* __restrict__ hb_out,
                                          int t, int c0) {
  for (int i = t; i < 1024; i += 256) {
    int b = i >> 5, cc = i & 31, d = c0 + cc;
    float gr = gi[i] + bih[d];
    float gz = gi[1024 + i] + bih[512 + d];
    float gn = gi[2048 + i] + bih[1024 + d];
    float hr = gh[b * 32 + cc] + bhh[d];
    float hz = gh[1024 + b * 32 + cc] + bhh[512 + d];
    float hn = gh[2048 + b * 32 + cc] + bhh[1024 + d];
    float r = sigm(gr + hr), z = sigm(gz + hz);
    float nn = tanhf(gn + r * hn);
    float hp = hF[b * 512 + d];
    float hnew = (1.f - z) * nn + z * hp;
    hF[b * 512 + d] = hnew;
    hb_out[b * 512 + d] = f2bf(hnew);
  }
}

// ---------------- persistent encoder scan v3.1 ----------------
// 16 blocks (col-split), Whh in REGISTERS (B-fragments), static 48KB LDS,
// double-buffered h exchange, acquire-poll sense barrier.
// FIX vs v3: n-gate uses r * (gh_n + bhh_n)  (the reset gating was dropped in v2/v3)
__global__ __launch_bounds__(256, 1) void k_enc_scan(
    const unsigned short* __restrict__ whhB, const float* __restrict__ giE,
    const float* __restrict__ bih, const float* __restrict__ bhh,
    float* __restrict__ hF, unsigned short* __restrict__ hbA,
    unsigned short* __restrict__ hbB, int* __restrict__ arr) {
  __shared__ unsigned short hb[32 * 512];  // 32 KB, XOR-swizzled
  __shared__ float gh[3 * 1024];           // 12 KB
  __shared__ float h32[1024];              // 4 KB
  int t = threadIdx.x, bid = blockIdx.x;
  int c0 = bid * 32;
  int lane = t & 63, g = t >> 6;
  int b31 = lane & 31, kg = lane >> 5;

  // preload Whh B-fragments into registers (waves 0..2; 32x short8 = 128 VGPR)
  short8 wreg[32];
  if (g < 3) {
    const unsigned short* brow = whhB + (size_t)(g * 512 + c0 + b31) * 512 + kg * 8;
#pragma unroll
    for (int kk = 0; kk < 32; ++kk) wreg[kk] = *(const short8*)(brow + kk * 16);
  }
  for (int i = t; i < 1024; i += 256) h32[i] = 0.f;
  int cc = t & 31, d = c0 + cc;
  float bi_r = bih[d], bi_z = bih[512 + d], bi_n = bih[1024 + d];
  float bh_r = bhh[d], bh_z = bhh[512 + d], bh_n = bhh[1024 + d];
  int asw = (b31 & 15) << 4;
  __syncthreads();

  for (int s = 0; s < T_STEPS; ++s) {
    const unsigned short* hbin = (s & 1) ? hbB : hbA;
    unsigned short* hbout = (s & 1) ? hbA : hbB;
    // gi prefetch to regs (constant data; overlaps the barrier wait)
    float gr_r[4], gz_r[4], gn_r[4];
#pragma unroll
    for (int j = 0; j < 4; ++j) {
      int b = (t >> 5) + 8 * j;
      const float* gp = giE + (size_t)(b * T_STEPS + s) * G3 + c0 + cc;
      gr_r[j] = gp[0]; gz_r[j] = gp[512]; gn_r[j] = gp[1024];
    }
    // wait: all blocks published h_s
    if (s > 0 && t < 64) {
      for (;;) {
        int v = __hip_atomic_load(&arr[t & 15], __ATOMIC_ACQUIRE, __HIP_MEMORY_SCOPE_AGENT);
        if (__all(v >= s)) break;
        __builtin_amdgcn_s_sleep(1);
      }
    }
    __syncthreads();
    stage_hb(hbin, hb, t);
    __syncthreads();
    // core: gh = h . Whh^T, B from registers
    if (g < 3) {
      f32x16 acc0, acc1;
#pragma unroll
      for (int q = 0; q < 16; ++q) { acc0[q] = 0.f; acc1[q] = 0.f; }
      const char* abase = (const char*)hb + b31 * 1024;
#pragma unroll
      for (int kk = 0; kk < 32; ++kk) {
        int kb = (kk * 32 + kg * 16) ^ asw;
        short8 a = *(const short8*)(abase + kb);
        if (kk & 1) acc1 = __builtin_amdgcn_mfma_f32_32x32x16_bf16(a, wreg[kk], acc1, 0, 0, 0);
        else acc0 = __builtin_amdgcn_mfma_f32_32x32x16_bf16(a, wreg[kk], acc0, 0, 0, 0);
      }
#pragma unroll
      for (int q = 0; q < 16; ++q) {
        int br = (q & 3) + 8 * (q >> 2) + 4 * kg;
        gh[g * 1024 + br * 32 + b31] = acc0[q] + acc1[q];
      }
    }
    __syncthreads();
    // gates (n-gate: r * (gh_n + bhh_n) — the fix)
#pragma unroll
    for (int j = 0; j < 4; ++j) {
      int i = t + 256 * j;
      int b = (t >> 5) + 8 * j;
      float r = sigm(gr_r[j] + bi_r + gh[i] + bh_r);
      float z = sigm(gz_r[j] + bi_z + gh[1024 + i] + bh_z);
      float nn = tanhf(gn_r[j] + bi_n + r * (gh[2048 + i] + bh_n));
      float hnew = (1.f - z) * nn + z * h32[i];
      h32[i] = hnew;
      hbout[b * 512 + d] = f2bf(hnew);
    }
    __syncthreads();           // all waves' stores drained
    if (t == 0) {
      __threadfence();         // write back so other XCDs see h_{s+1}
      __hip_atomic_store(&arr[bid], s + 1, __ATOMIC_RELEASE, __HIP_MEMORY_SCOPE_AGENT);
    }
  }
  // final h -> hF (f32) for decoder
#pragma unroll
  for (int j = 0; j < 4; ++j) {
    int i = t + 256 * j;
    int b = (t >> 5) + 8 * j;
    hF[b * 512 + d] = h32[i];
  }
}

// ---------------- decoder GRU step (one launch per step; 16 blocks) ----------------
__global__ __launch_bounds__(256) void k_gru_dec(
    const unsigned short* __restrict__ whhB, const float* __restrict__ parts,
    const float* __restrict__ bih, const float* __restrict__ bhh,
    float* hF, const unsigned short* __restrict__ hb_in, unsigned short* __restrict__ hb_out) {
  __shared__ unsigned short hb[32 * 512];
  __shared__ float gh[3 * 32 * 32];
  __shared__ float gi[3 * 32 * 32];
  int t = threadIdx.x;
  int c0 = blockIdx.x * 32;
  stage_hb(hb_in, hb, t);
  for (int i = t; i < 3072; i += 256) {
    int gg = i >> 10, r = i & 1023, bb = r >> 5, cc = r & 31;
    int dd = gg * 512 + c0 + cc;
    float a = 0.f;
#pragma unroll 4
    for (int kc = 0; kc < 20; ++kc) a += parts[(size_t)kc * (NB * G3) + bb * G3 + dd];
    gi[i] = a;
  }
  __syncthreads();
  gru_core_g(whhB, hb, gh, t, c0);
  __syncthreads();
  gru_gates(gi, gh, bih, bhh, hF, hb_out, t, c0);
}

// ---------------- decoder gi GEMM: parts[kc] = E8(32x8000,on-the-fly) . Wih^T ----------------
__global__ __launch_bounds__(256) void k_dec_gemm(
    const unsigned short* __restrict__ wihD, const float* __restrict__ sbuf,
    const float* __restrict__ Wd, const float* __restrict__ bd,
    float* __restrict__ parts) {
  __shared__ float s_lds[32 * 26];
  int t = threadIdx.x;
  int ntile = blockIdx.x, kc = blockIdx.y;  // (12, 20)
  for (int i = t; i < 800; i += 256) {
    int b = i / 25, nn = i - b * 25;
    s_lds[b * 26 + nn] = sbuf[b * N_NODES + kc * 25 + nn];
  }
  int lane = t & 63, w = t >> 6;
  int b31 = lane & 31, kg = lane >> 5;
  float wd8[8], bd8[8];
#pragma unroll
  for (int j = 0; j < 8; ++j) { wd8[j] = Wd[kg * 8 + j]; bd8[j] = bd[kg * 8 + j]; }
  __syncthreads();
  f32x16 acc;
#pragma unroll
  for (int q = 0; q < 16; ++q) acc[q] = 0.f;
  const unsigned short* brow = wihD + (size_t)(ntile * 128 + w * 32 + b31) * NH + kc * 400 + kg * 8;
  for (int kk = 0; kk < 25; ++kk) {
    float sv = s_lds[b31 * 26 + kk];
    short8 av;
#pragma unroll
    for (int j = 0; j < 8; ++j) av[j] = (short)f2bf(fmaxf(sv * wd8[j] + bd8[j], 0.f));
    short8 bv = *(const short8*)(brow + kk * 16);
    acc = __builtin_amdgcn_mfma_f32_32x32x16_bf16(av, bv, acc, 0, 0, 0);
  }
  int colo = ntile * 128 + w * 32 + b31;
#pragma unroll
  for (int q = 0; q < 16; ++q) {
    int br = (q & 3) + 8 * (q >> 2) + 4 * kg;
    parts[(size_t)kc * (NB * G3) + br * G3 + colo] = acc[q];
  }
}

// ---------------- fc + out-aggregation fused (per-b block) ----------------
__global__ __launch_bounds__(256) void k_fc_agg(
    const float* __restrict__ hF, const float* __restrict__ fcW, const float* __restrict__ fcb,
    const int* __restrict__ rowptr, const int* __restrict__ col, const float* __restrict__ nrm,
    float* __restrict__ out, float* __restrict__ sbuf, int s) {
  __shared__ float hrow[512];
  __shared__ float orow[N_NODES];
  int b = blockIdx.x, t = threadIdx.x;
  hrow[t] = hF[b * 512 + t];
  hrow[t + 256] = hF[b * 512 + t + 256];
  __syncthreads();
  for (int n = t; n < N_NODES; n += 256) {
    const float4* wr = (const float4*)(fcW + (size_t)n * DH);
    float a = 0.f;
#pragma unroll 4
    for (int k = 0; k < 128; ++k) {
      float4 wv = wr[k];
      const float4 hv = *(const float4*)&hrow[k * 4];
      a += wv.x * hv.x + wv.y * hv.y + wv.z * hv.z + wv.w * hv.w;
    }
    float o = a + fcb[n];
    orow[n] = o;
    out[(size_t)b * (DSTEPS * N_NODES) + s * N_NODES + n] = o;
  }
  __syncthreads();
  for (int n = t; n < N_NODES; n += 256) {
    int e1 = rowptr[n + 1];
    float a = 0.f;
    for (int e = rowptr[n]; e < e1; ++e) a += nrm[e] * orow[col[e]];
    sbuf[b * N_NODES + n] = a;
  }
}

// ---------------- initial decoder aggregation ----------------
__global__ __launch_bounds__(256) void k_agg0(
    const float* __restrict__ dec0, const int* __restrict__ rowptr,
    const int* __restrict__ col, const float* __restrict__ nrm, float* __restrict__ sbuf) {
  __shared__ float irow[N_NODES];
  int b = blockIdx.x, t = threadIdx.x;
  for (int n = t; n < N_NODES; n += 256) irow[n] = dec0[b * N_NODES + n];
  __syncthreads();
  for (int n = t; n < N_NODES; n += 256) {
    int e1 = rowptr[n + 1];
    float a = 0.f;
    for (int e = rowptr[n]; e < e1; ++e) a += nrm[e] * irow[col[e]];
    sbuf[b * N_NODES + n] = a;
  }
}

extern "C" void kernel_launch(void* const* d_in, const int* in_sizes, int n_in,
                              void* d_out, int out_size, void* d_ws, size_t ws_size,
                              hipStream_t stream) {
  const float* x = (const float*)d_in[0];
  const float* dec0 = (const float*)d_in[1];
  const int* ei = (const int*)d_in[2];
  const float* gWe = (const float*)d_in[3];
  const float* gbe = (const float*)d_in[4];
  const float* gWd = (const float*)d_in[5];
  const float* gbd = (const float*)d_in[6];
  const float* eWih = (const float*)d_in[7];
  const float* eWhh = (const float*)d_in[8];
  const float* ebih = (const float*)d_in[9];
  const float* ebhh = (const float*)d_in[10];
  const float* dWih = (const float*)d_in[11];
  const float* dWhh = (const float*)d_in[12];
  const float* dbih = (const float*)d_in[13];
  const float* dbhh = (const float*)d_in[14];
  const float* fcW = (const float*)d_in[15];
  const float* fcb = (const float*)d_in[16];
  float* out = (float*)d_out;
  (void)in_sizes; (void)n_in; (void)out_size; (void)ws_size;

  char* w = (char*)d_ws;
  size_t off = 0;
  auto alloc = [&](size_t bytes) -> void* {
    void* p = w + off;
    off = (off + bytes + 255) & ~(size_t)255;
    return p;
  };
  int* deg = (int*)alloc(512 * 4);
  float* dinv = (float*)alloc(512 * 4);
  int* rowptr = (int*)alloc(512 * 4);
  int* cursor = (int*)alloc(512 * 4);
  int* colA = (int*)alloc(E_TOT * 4);
  float* nrmA = (float*)alloc(E_TOT * 4);
  unsigned short* whhE = (unsigned short*)alloc((size_t)G3 * DH * 2);
  unsigned short* whhD = (unsigned short*)alloc((size_t)G3 * DH * 2);
  unsigned short* AhatD = (unsigned short*)alloc(512 * 512 * 2);
  float* hF = (float*)alloc(NB * DH * 4);                     // | contiguous:
  unsigned short* hbX = (unsigned short*)alloc(NB * DH * 2);  // | one memset
  int* arr = (int*)alloc(256);                                // |
  unsigned short* hbY = (unsigned short*)alloc(NB * DH * 2);
  float* sbuf = (float*)alloc((size_t)NB * N_NODES * 4);
  unsigned short* emb = (unsigned short*)alloc((size_t)BT * NH * 2);
  char* wihE_parts = (char*)alloc((size_t)G3 * NH * 2);   // wihE, later parts
  unsigned short* wihE = (unsigned short*)wihE_parts;
  float* parts = (float*)wihE_parts;
  unsigned short* wihD = (unsigned short*)alloc((size_t)G3 * NH * 2);
  char* xT2_giE = (char*)alloc((size_t)16384 * 512 * 2);  // xT2, later giE
  unsigned short* xT2 = (unsigned short*)xT2_giE;
  float* giE = (float*)xT2_giE;

  // zero hF + hbX + arr (contiguous region)
  hipMemsetAsync(hF, 0, NB * DH * 4 + NB * DH * 2 + 256, stream);

  k_deg_init<<<2, 256, 0, stream>>>(deg);
  k_deg_count<<<(E_EDGES + 255) / 256, 256, 0, stream>>>(ei, deg);
  k_scan<<<1, 512, 0, stream>>>(deg, dinv, rowptr, cursor);
  k_scatter<<<(E_TOT + 255) / 256, 256, 0, stream>>>(ei, dinv, cursor, colA, nrmA);

  int n4w = G3 * NH / 4;
  int n4h = G3 * DH / 4;
  k_f2bf4<<<(n4w + 255) / 256, 256, 0, stream>>>(eWih, wihE, n4w);
  k_f2bf4<<<(n4w + 255) / 256, 256, 0, stream>>>(dWih, wihD, n4w);
  k_f2bf4<<<(n4h + 255) / 256, 256, 0, stream>>>(eWhh, whhE, n4h);
  k_f2bf4<<<(n4h + 255) / 256, 256, 0, stream>>>(dWhh, whhD, n4h);

  k_transpose<<<BT, 256, 0, stream>>>(x, xT2);
  k_densify<<<512, 256, 0, stream>>>(rowptr, colA, nrmA, AhatD);
  k_gemm_agg<<<dim3(128, 4), 256, 0, stream>>>(xT2, AhatD, gWe, gbe, emb);

  k_gemm_enc<<<dim3(BT / 128, G3 / 128), 256, 0, stream>>>(emb, wihE, giE);

  k_enc_scan<<<16, 256, 0, stream>>>(whhE, giE, ebih, ebhh, hF, hbX, hbY, arr);

  k_agg0<<<NB, 256, 0, stream>>>(dec0, rowptr, colA, nrmA, sbuf);

  for (int s = 0; s < DSTEPS; ++s) {
    const unsigned short* hbin = (s & 1) ? hbY : hbX;
    unsigned short* hbout = (s & 1) ? hbX : hbY;
    k_dec_gemm<<<dim3(12, 20), 256, 0, stream>>>(wihD, sbuf, gWd, gbd, parts);
    k_gru_dec<<<16, 256, 0, stream>>>(whhD, parts, dbih, dbhh, hF, hbin, hbout);
    k_fc_agg<<<NB, 256, 0, stream>>>(hF, fcW, fcb, rowptr, colA, nrmA, out, sbuf, s);
  }
}

// Round 6
// 2065.406 us; speedup vs baseline: 1.3398x; 1.0070x over previous
//
#include <hip/hip_runtime.h>
#include <stdint.h>

typedef short short8 __attribute__((ext_vector_type(8)));
typedef float f32x4 __attribute__((ext_vector_type(4)));
typedef float f32x16 __attribute__((ext_vector_type(16)));

#define N_NODES 500
#define HGC 16
#define DH 512
#define T_STEPS 64
#define NB 32
#define F_IN 8
#define DSTEPS 16
#define E_EDGES 16000
#define E_TOT 16500
#define NH 8000          // N*HG
#define G3 1536          // 3*D
#define BT 2048          // B*T

__device__ __forceinline__ unsigned short f2bf(float x) {
  unsigned int u = __float_as_uint(x);
  u = (u + 0x7fffu + ((u >> 16) & 1u)) >> 16;
  return (unsigned short)u;
}

__device__ __forceinline__ void gl_lds16(const void* g, void* l) {
  __builtin_amdgcn_global_load_lds((const __attribute__((address_space(1))) void*)g,
                                   (__attribute__((address_space(3))) void*)l, 16, 0, 0);
}

__device__ __forceinline__ float sigm(float x) { return 1.f / (1.f + __expf(-x)); }

// ---------------- graph prep ----------------
__global__ void k_deg_init(int* deg) {
  int t = blockIdx.x * blockDim.x + threadIdx.x;
  if (t < N_NODES) deg[t] = 1;  // self loop
}

__global__ void k_deg_count(const int* __restrict__ ei, int* deg) {
  int t = blockIdx.x * blockDim.x + threadIdx.x;
  if (t < E_EDGES) atomicAdd(&deg[ei[E_EDGES + t]], 1);
}

__global__ void k_scan(const int* __restrict__ deg, float* dinv, int* rowptr, int* cursor) {
  __shared__ int s[512];
  int t = threadIdx.x;
  int v = (t < N_NODES) ? deg[t] : 0;
  s[t] = v;
  __syncthreads();
  for (int off = 1; off < 512; off <<= 1) {
    int add = (t >= off) ? s[t - off] : 0;
    __syncthreads();
    s[t] += add;
    __syncthreads();
  }
  if (t < N_NODES) {
    int excl = s[t] - v;
    rowptr[t] = excl;
    cursor[t] = excl;
    dinv[t] = rsqrtf((float)v);
  }
  if (t == 0) rowptr[N_NODES] = s[511];
}

__global__ void k_scatter(const int* __restrict__ ei, const float* __restrict__ dinv,
                          int* cursor, int* col, float* nrm) {
  int t = blockIdx.x * blockDim.x + threadIdx.x;
  if (t >= E_TOT) return;
  int s_, d_;
  if (t < E_EDGES) { s_ = ei[t]; d_ = ei[E_EDGES + t]; }
  else { s_ = d_ = t - E_EDGES; }
  int pos = atomicAdd(&cursor[d_], 1);
  col[pos] = s_;
  nrm[pos] = dinv[s_] * dinv[d_];
}

// ---------------- f32 -> bf16 bulk convert ----------------
__global__ void k_f2bf4(const float* __restrict__ src, unsigned short* __restrict__ dst, int n4) {
  int i = blockIdx.x * blockDim.x + threadIdx.x;
  if (i >= n4) return;
  float4 v = ((const float4*)src)[i];
  ushort4 o;
  o.x = f2bf(v.x); o.y = f2bf(v.y); o.z = f2bf(v.z); o.w = f2bf(v.w);
  ((ushort4*)dst)[i] = o;
}

// ---------------- x (2048,500,8) f32 -> xT2 (16384, 512) bf16 (zero-padded cols) ----------------
__global__ __launch_bounds__(256) void k_transpose(const float* __restrict__ x,
                                                   unsigned short* __restrict__ xT2) {
  __shared__ float xs[N_NODES * 9];
  int g = blockIdx.x, t = threadIdx.x;
  const float4* xg = (const float4*)(x + (size_t)g * (N_NODES * F_IN));
  for (int i = t; i < N_NODES * 2; i += 256) {
    float4 v = xg[i];
    int n = i >> 1, fh = (i & 1) * 4;
    float* d = &xs[n * 9 + fh];
    d[0] = v.x; d[1] = v.y; d[2] = v.z; d[3] = v.w;
  }
  __syncthreads();
  int f = t >> 5, u = t & 31;
  short8 lo, hi;
#pragma unroll
  for (int j = 0; j < 8; ++j) {
    int n0 = u * 16 + j, n1 = n0 + 8;
    lo[j] = (short)((n0 < N_NODES) ? f2bf(xs[n0 * 9 + f]) : 0);
    hi[j] = (short)((n1 < N_NODES) ? f2bf(xs[n1 * 9 + f]) : 0);
  }
  unsigned short* dst = xT2 + (size_t)(g * 8 + f) * 512 + u * 16;
  *(short8*)dst = lo;
  *(short8*)(dst + 8) = hi;
}

// ---------------- densify Ahat rows (by dst) -> (512, 512) bf16 ----------------
__global__ __launch_bounds__(256) void k_densify(const int* __restrict__ rowptr,
                                                 const int* __restrict__ col,
                                                 const float* __restrict__ nrm,
                                                 unsigned short* __restrict__ AhatD) {
  __shared__ float row[512];
  int n = blockIdx.x, t = threadIdx.x;
  row[t] = 0.f; row[t + 256] = 0.f;
  __syncthreads();
  if (n < N_NODES) {
    int e1 = rowptr[n + 1];
    for (int e = rowptr[n] + t; e < e1; e += 256) atomicAdd(&row[col[e]], nrm[e]);
  }
  __syncthreads();
  AhatD[n * 512 + t] = f2bf(row[t]);
  AhatD[n * 512 + t + 256] = f2bf(row[t + 256]);
}

// ---------------- agg GEMM: C(16384 gf, 512 n) = xT2 . AhatD^T ; fused W(8->16)+relu -> emb ----------------
__global__ __launch_bounds__(256) void k_gemm_agg(const unsigned short* __restrict__ A,
                                                  const unsigned short* __restrict__ B,
                                                  const float* __restrict__ W,
                                                  const float* __restrict__ bias,
                                                  unsigned short* __restrict__ emb) {
  __shared__ float smem[64 * 129];
  __shared__ float Wsm[F_IN * HGC];
  __shared__ float bsm[HGC];
  unsigned short* As = (unsigned short*)smem;
  unsigned short* Bs = As + 4096;
  int t = threadIdx.x;
  if (t < F_IN * HGC) Wsm[t] = W[t];
  if (t < HGC) bsm[t] = bias[t];
  int m0 = blockIdx.x * 128, n0 = blockIdx.y * 128;
  int wave = t >> 6, lane = t & 63;
  int mh = (wave >> 1) * 64, nh = (wave & 1) * 64;
  int lrow = t >> 2, lslot = t & 3;
  f32x4 acc[4][4];
#pragma unroll
  for (int a = 0; a < 4; ++a)
#pragma unroll
    for (int b = 0; b < 4; ++b) acc[a][b] = (f32x4){0.f, 0.f, 0.f, 0.f};
  const unsigned short* ga0 = A + (size_t)(m0 + lrow) * 512 + lslot * 8;
  const unsigned short* ga1 = A + (size_t)(m0 + 64 + lrow) * 512 + lslot * 8;
  const unsigned short* gb0 = B + (size_t)(n0 + lrow) * 512 + lslot * 8;
  const unsigned short* gb1 = B + (size_t)(n0 + 64 + lrow) * 512 + lslot * 8;
  int rl = lane & 15, ks = lane >> 4;
  for (int kt = 0; kt < 16; ++kt) {
    int k0 = kt * 32;
    gl_lds16(ga0 + k0, &As[t * 8]);
    gl_lds16(ga1 + k0, &As[2048 + t * 8]);
    gl_lds16(gb0 + k0, &Bs[t * 8]);
    gl_lds16(gb1 + k0, &Bs[2048 + t * 8]);
    __syncthreads();
    short8 af[4], bfr[4];
#pragma unroll
    for (int mf = 0; mf < 4; ++mf) af[mf] = *(const short8*)&As[(mh + mf * 16 + rl) * 32 + ks * 8];
#pragma unroll
    for (int nf = 0; nf < 4; ++nf) bfr[nf] = *(const short8*)&Bs[(nh + nf * 16 + rl) * 32 + ks * 8];
#pragma unroll
    for (int mf = 0; mf < 4; ++mf)
#pragma unroll
      for (int nf = 0; nf < 4; ++nf)
        acc[mf][nf] = __builtin_amdgcn_mfma_f32_16x16x32_bf16(af[mf], bfr[nf], acc[mf][nf], 0, 0, 0);
    __syncthreads();
  }
  int rg = lane >> 4;
  for (int p = 0; p < 2; ++p) {
    if ((wave >> 1) == p) {
#pragma unroll
      for (int mf = 0; mf < 4; ++mf)
#pragma unroll
        for (int nf = 0; nf < 4; ++nf)
#pragma unroll
          for (int q = 0; q < 4; ++q)
            smem[(mf * 16 + rg * 4 + q) * 129 + nh + nf * 16 + rl] = acc[mf][nf][q];
    }
    __syncthreads();
    int gl = t >> 5, sub = t & 31;
    int g = blockIdx.x * 16 + p * 8 + gl;
#pragma unroll
    for (int j = 0; j < 4; ++j) {
      int nl = sub + 32 * j, ng = n0 + nl;
      if (ng < N_NODES) {
        float v[8];
#pragma unroll
        for (int f = 0; f < 8; ++f) v[f] = smem[(gl * 8 + f) * 129 + nl];
        short8 o0, o1;
#pragma unroll
        for (int c = 0; c < 8; ++c) {
          float s0 = bsm[c], s1 = bsm[c + 8];
#pragma unroll
          for (int f = 0; f < 8; ++f) {
            s0 += v[f] * Wsm[f * 16 + c];
            s1 += v[f] * Wsm[f * 16 + c + 8];
          }
          o0[c] = (short)f2bf(fmaxf(s0, 0.f));
          o1[c] = (short)f2bf(fmaxf(s1, 0.f));
        }
        unsigned short* dst = emb + (size_t)g * NH + ng * 16;
        *(short8*)dst = o0;
        *(short8*)(dst + 8) = o1;
      }
    }
    __syncthreads();
  }
}

// ---------------- big encoder GEMM: gi = emb(2048x8000) . Wih(1536x8000)^T ----------------
// 128(M)x64(N) tiles, grid (16,24)=384 blocks. Writes DIRECTLY into scan layout:
// giP2[s][blk][gate][b][cc]  (s=m&63, b=m>>6; gate=n>>9, d=n&511, blk=d>>5, cc=d&31)
__global__ __launch_bounds__(256) void k_gemm_enc(
    const unsigned short* __restrict__ A, const unsigned short* __restrict__ Bm,
    float* __restrict__ giP2) {
  __shared__ unsigned short As[128 * 32];
  __shared__ unsigned short Bs[64 * 32];
  int t = threadIdx.x;
  int m0 = blockIdx.x * 128, n0 = blockIdx.y * 64;
  int wave = t >> 6, lane = t & 63;
  int mh = (wave >> 1) * 64, nh = (wave & 1) * 32;
  int lrow = t >> 2, lslot = t & 3;
  f32x4 acc[4][2];
#pragma unroll
  for (int a = 0; a < 4; ++a)
#pragma unroll
    for (int b = 0; b < 2; ++b) acc[a][b] = (f32x4){0.f, 0.f, 0.f, 0.f};
  const unsigned short* ga0 = A + (size_t)(m0 + lrow) * NH + lslot * 8;
  const unsigned short* ga1 = A + (size_t)(m0 + 64 + lrow) * NH + lslot * 8;
  const unsigned short* gb0 = Bm + (size_t)(n0 + lrow) * NH + lslot * 8;
  int rl = lane & 15, ks = lane >> 4;
  for (int kt = 0; kt < 250; ++kt) {
    int k0 = kt * 32;
    gl_lds16(ga0 + k0, &As[t * 8]);
    gl_lds16(ga1 + k0, &As[2048 + t * 8]);
    gl_lds16(gb0 + k0, &Bs[t * 8]);
    __syncthreads();
    short8 af[4], bfr[2];
#pragma unroll
    for (int mf = 0; mf < 4; ++mf) af[mf] = *(const short8*)&As[(mh + mf * 16 + rl) * 32 + ks * 8];
#pragma unroll
    for (int nf = 0; nf < 2; ++nf) bfr[nf] = *(const short8*)&Bs[(nh + nf * 16 + rl) * 32 + ks * 8];
#pragma unroll
    for (int mf = 0; mf < 4; ++mf)
#pragma unroll
      for (int nf = 0; nf < 2; ++nf)
        acc[mf][nf] = __builtin_amdgcn_mfma_f32_16x16x32_bf16(af[mf], bfr[nf], acc[mf][nf], 0, 0, 0);
    __syncthreads();
  }
  int rg = lane >> 4;
  int gate = n0 >> 9;          // uniform per block (tile never crosses a 512 boundary)
#pragma unroll
  for (int mf = 0; mf < 4; ++mf)
#pragma unroll
    for (int nf = 0; nf < 2; ++nf) {
      int n = n0 + nh + nf * 16 + rl;
      int d = n & 511, blk = d >> 5, cc = d & 31;
#pragma unroll
      for (int q = 0; q < 4; ++q) {
        int m = m0 + mh + mf * 16 + rg * 4 + q;
        int s = m & 63, bb = m >> 6;
        giP2[(size_t)(s * 16 + blk) * 3072 + gate * 1024 + bb * 32 + cc] = acc[mf][nf][q];
      }
    }
}

// ---------------- shared GRU helpers ----------------
// stage h (32x512 bf16) from global into LDS with (row&15)<<4 XOR swizzle
__device__ __forceinline__ void stage_hb(const unsigned short* __restrict__ src,
                                         unsigned short* hb, int t) {
  int bw = t >> 3, i8 = t & 7;
  short8 v[8];
#pragma unroll
  for (int i = 0; i < 8; ++i)
    v[i] = *(const short8*)((const char*)src + bw * 1024 + i8 * 128 + i * 16);
#pragma unroll
  for (int i = 0; i < 8; ++i) {
    int kb = i8 * 128 + i * 16;
    *(short8*)((char*)hb + bw * 1024 + (kb ^ ((bw & 15) << 4))) = v[i];
  }
}

// decoder: gh = h(32x512 LDS swz) . Whh^T (B from global)
__device__ __forceinline__ void gru_core_g(const unsigned short* __restrict__ whhB,
                                           const unsigned short* hb, float* gh,
                                           int t, int c0) {
  int lane = t & 63, g = t >> 6;
  int b31 = lane & 31, kg = lane >> 5;
  if (g < 3) {
    f32x16 acc;
#pragma unroll
    for (int q = 0; q < 16; ++q) acc[q] = 0.f;
    const unsigned short* brow = whhB + (size_t)(g * 512 + c0 + b31) * 512 + kg * 8;
    int asw = (b31 & 15) << 4;
#pragma unroll 4
    for (int kk = 0; kk < 32; ++kk) {
      int kb = (kk * 32 + kg * 16) ^ asw;
      short8 a = *(const short8*)((const char*)hb + b31 * 1024 + kb);
      short8 b = *(const short8*)(brow + kk * 16);
      acc = __builtin_amdgcn_mfma_f32_32x32x16_bf16(a, b, acc, 0, 0, 0);
    }
#pragma unroll
    for (int q = 0; q < 16; ++q) {
      int br = (q & 3) + 8 * (q >> 2) + 4 * kg;
      gh[g * 1024 + br * 32 + b31] = acc[q];
    }
  }
}

// decoder gates (reads gi LDS, hF global prev-h; writes hF + bf16 h)
__device__ __forceinline__ void gru_gates(const float* gi, const float* gh,
                                          const float* __restrict__ bih,
                                          const float* __restrict__ bhh,
                                          float* __restrict__ hF,
                                          unsigned short* __restrict__ hb_out,
                                          int t, int c0) {
  for (int i = t; i < 1024; i += 256) {
    int b = i >> 5, cc = i & 31, d = c0 + cc;
    float gr = gi[i] + bih[d];
    float gz = gi[1024 + i] + bih[512 + d];
    float gn = gi[2048 + i] + bih[1024 + d];
    float hr = gh[b * 32 + cc] + bhh[d];
    float hz = gh[1024 + b * 32 + cc] + bhh[512 + d];
    float hn = gh[2048 + b * 32 + cc] + bhh[1024 + d];
    float r = sigm(gr + hr), z = sigm(gz + hz);
    float nn = tanhf(gn + r * hn);
    float hp = hF[b * 512 + d];
    float hnew = (1.f - z) * nn + z * hp;
    hF[b * 512 + d] = hnew;
    hb_out[b * 512 + d] = f2bf(hnew);
  }
}

// ---------------- persistent encoder scan v4 ----------------
// 16 blocks (col-split), Whh in REGISTERS, gi prefetched one step ahead into LDS
// via global_load_lds (contiguous giP2 blobs), relaxed poll + single fence.
__global__ __launch_bounds__(256, 1) void k_enc_scan(
    const unsigned short* __restrict__ whhB, const float* __restrict__ giP2,
    const float* __restrict__ bih, const float* __restrict__ bhh,
    float* __restrict__ hF, unsigned short* __restrict__ hbA,
    unsigned short* __restrict__ hbB, int* __restrict__ arr) {
  __shared__ unsigned short hb[32 * 512];  // 32 KB, XOR-swizzled
  __shared__ float gh[3 * 1024];           // 12 KB
  __shared__ float h32[1024];              // 4 KB
  __shared__ float gi_lds[3072];           // 12 KB (prefetch buffer)
  int t = threadIdx.x, bid = blockIdx.x;
  int c0 = bid * 32;
  int lane = t & 63, g = t >> 6;
  int b31 = lane & 31, kg = lane >> 5;

  // preload Whh B-fragments into registers (waves 0..2; 32x short8 = 128 VGPR)
  short8 wreg[32];
  if (g < 3) {
    const unsigned short* brow = whhB + (size_t)(g * 512 + c0 + b31) * 512 + kg * 8;
#pragma unroll
    for (int kk = 0; kk < 32; ++kk) wreg[kk] = *(const short8*)(brow + kk * 16);
  }
  for (int i = t; i < 1024; i += 256) h32[i] = 0.f;
  int cc = t & 31, d = c0 + cc;
  float bi_r = bih[d], bi_z = bih[512 + d], bi_n = bih[1024 + d];
  float bh_r = bhh[d], bh_z = bhh[512 + d], bh_n = bhh[1024 + d];
  int asw = (b31 & 15) << 4;
  // prologue: prefetch gi for s=0 (3 chunks of 16B per thread)
  {
    const float* src0 = giP2 + (size_t)bid * 3072;
#pragma unroll
    for (int i = 0; i < 3; ++i)
      gl_lds16(src0 + i * 1024 + t * 4, &gi_lds[i * 1024 + t * 4]);
  }
  __syncthreads();  // drains gi[0] prefetch (vmcnt at barrier)

  for (int s = 0; s < T_STEPS; ++s) {
    const unsigned short* hbin = (s & 1) ? hbB : hbA;
    unsigned short* hbout = (s & 1) ? hbA : hbB;
    // wait: all blocks published h_s (relaxed poll + one acquire fence)
    if (s > 0 && t < 64) {
      for (;;) {
        int v = __hip_atomic_load(&arr[t & 15], __ATOMIC_RELAXED, __HIP_MEMORY_SCOPE_AGENT);
        if (__all(v >= s)) break;
        __builtin_amdgcn_s_sleep(1);
      }
      __threadfence();  // invalidate stale cached h
    }
    __syncthreads();    // also drains gi prefetch issued at end of prev step
    stage_hb(hbin, hb, t);
    __syncthreads();
    // core: gh = h . Whh^T, B from registers
    if (g < 3) {
      f32x16 acc0, acc1;
#pragma unroll
      for (int q = 0; q < 16; ++q) { acc0[q] = 0.f; acc1[q] = 0.f; }
      const char* abase = (const char*)hb + b31 * 1024;
#pragma unroll
      for (int kk = 0; kk < 32; ++kk) {
        int kb = (kk * 32 + kg * 16) ^ asw;
        short8 a = *(const short8*)(abase + kb);
        if (kk & 1) acc1 = __builtin_amdgcn_mfma_f32_32x32x16_bf16(a, wreg[kk], acc1, 0, 0, 0);
        else acc0 = __builtin_amdgcn_mfma_f32_32x32x16_bf16(a, wreg[kk], acc0, 0, 0, 0);
      }
#pragma unroll
      for (int q = 0; q < 16; ++q) {
        int br = (q & 3) + 8 * (q >> 2) + 4 * kg;
        gh[g * 1024 + br * 32 + b31] = acc0[q] + acc1[q];
      }
    }
    __syncthreads();
    // gates (n-gate: r * (gh_n + bhh_n))
#pragma unroll
    for (int j = 0; j < 4; ++j) {
      int i = t + 256 * j;
      int b = (t >> 5) + 8 * j;
      float r = sigm(gi_lds[i] + bi_r + gh[i] + bh_r);
      float z = sigm(gi_lds[1024 + i] + bi_z + gh[1024 + i] + bh_z);
      float nn = tanhf(gi_lds[2048 + i] + bi_n + r * (gh[2048 + i] + bh_n));
      float hnew = (1.f - z) * nn + z * h32[i];
      h32[i] = hnew;
      hbout[b * 512 + d] = f2bf(hnew);
    }
    __syncthreads();           // gi reads done + hbout stores drained
    // prefetch gi for s+1 (wave 3, idle during MFMA; overlaps publish + poll + stage)
    if (g == 3 && s + 1 < T_STEPS) {
      const float* srcn = giP2 + (size_t)((s + 1) * 16 + bid) * 3072;
#pragma unroll
      for (int i = 0; i < 12; ++i)
        gl_lds16(srcn + (i * 64 + lane) * 4, &gi_lds[(i * 64 + lane) * 4]);
    }
    if (t == 0) {
      __threadfence();         // write back so other XCDs see h_{s+1}
      __hip_atomic_store(&arr[bid], s + 1, __ATOMIC_RELEASE, __HIP_MEMORY_SCOPE_AGENT);
    }
  }
  // final h -> hF (f32) for decoder
#pragma unroll
  for (int j = 0; j < 4; ++j) {
    int i = t + 256 * j;
    int b = (t >> 5) + 8 * j;
    hF[b * 512 + d] = h32[i];
  }
}

// ---------------- decoder GRU step (one launch per step; 16 blocks) ----------------
__global__ __launch_bounds__(256) void k_gru_dec(
    const unsigned short* __restrict__ whhB, const float* __restrict__ parts,
    const float* __restrict__ bih, const float* __restrict__ bhh,
    float* hF, const unsigned short* __restrict__ hb_in, unsigned short* __restrict__ hb_out) {
  __shared__ unsigned short hb[32 * 512];
  __shared__ float gh[3 * 32 * 32];
  __shared__ float gi[3 * 32 * 32];
  int t = threadIdx.x;
  int c0 = blockIdx.x * 32;
  stage_hb(hb_in, hb, t);
  for (int i = t; i < 3072; i += 256) {
    int gg = i >> 10, r = i & 1023, bb = r >> 5, cc = r & 31;
    int dd = gg * 512 + c0 + cc;
    float a = 0.f;
#pragma unroll 4
    for (int kc = 0; kc < 20; ++kc) a += parts[(size_t)kc * (NB * G3) + bb * G3 + dd];
    gi[i] = a;
  }
  __syncthreads();
  gru_core_g(whhB, hb, gh, t, c0);
  __syncthreads();
  gru_gates(gi, gh, bih, bhh, hF, hb_out, t, c0);
}

// ---------------- decoder gi GEMM: parts[kc] = E8(32x8000,on-the-fly) . Wih^T ----------------
__global__ __launch_bounds__(256) void k_dec_gemm(
    const unsigned short* __restrict__ wihD, const float* __restrict__ sbuf,
    const float* __restrict__ Wd, const float* __restrict__ bd,
    float* __restrict__ parts) {
  __shared__ float s_lds[32 * 26];
  int t = threadIdx.x;
  int ntile = blockIdx.x, kc = blockIdx.y;  // (12, 20)
  for (int i = t; i < 800; i += 256) {
    int b = i / 25, nn = i - b * 25;
    s_lds[b * 26 + nn] = sbuf[b * N_NODES + kc * 25 + nn];
  }
  int lane = t & 63, w = t >> 6;
  int b31 = lane & 31, kg = lane >> 5;
  float wd8[8], bd8[8];
#pragma unroll
  for (int j = 0; j < 8; ++j) { wd8[j] = Wd[kg * 8 + j]; bd8[j] = bd[kg * 8 + j]; }
  __syncthreads();
  f32x16 acc;
#pragma unroll
  for (int q = 0; q < 16; ++q) acc[q] = 0.f;
  const unsigned short* brow = wihD + (size_t)(ntile * 128 + w * 32 + b31) * NH + kc * 400 + kg * 8;
  for (int kk = 0; kk < 25; ++kk) {
    float sv = s_lds[b31 * 26 + kk];
    short8 av;
#pragma unroll
    for (int j = 0; j < 8; ++j) av[j] = (short)f2bf(fmaxf(sv * wd8[j] + bd8[j], 0.f));
    short8 bv = *(const short8*)(brow + kk * 16);
    acc = __builtin_amdgcn_mfma_f32_32x32x16_bf16(av, bv, acc, 0, 0, 0);
  }
  int colo = ntile * 128 + w * 32 + b31;
#pragma unroll
  for (int q = 0; q < 16; ++q) {
    int br = (q & 3) + 8 * (q >> 2) + 4 * kg;
    parts[(size_t)kc * (NB * G3) + br * G3 + colo] = acc[q];
  }
}

// ---------------- fc + out-aggregation fused (per-b block) ----------------
__global__ __launch_bounds__(256) void k_fc_agg(
    const float* __restrict__ hF, const float* __restrict__ fcW, const float* __restrict__ fcb,
    const int* __restrict__ rowptr, const int* __restrict__ col, const float* __restrict__ nrm,
    float* __restrict__ out, float* __restrict__ sbuf, int s) {
  __shared__ float hrow[512];
  __shared__ float orow[N_NODES];
  int b = blockIdx.x, t = threadIdx.x;
  hrow[t] = hF[b * 512 + t];
  hrow[t + 256] = hF[b * 512 + t + 256];
  __syncthreads();
  for (int n = t; n < N_NODES; n += 256) {
    const float4* wr = (const float4*)(fcW + (size_t)n * DH);
    float a = 0.f;
#pragma unroll 4
    for (int k = 0; k < 128; ++k) {
      float4 wv = wr[k];
      const float4 hv = *(const float4*)&hrow[k * 4];
      a += wv.x * hv.x + wv.y * hv.y + wv.z * hv.z + wv.w * hv.w;
    }
    float o = a + fcb[n];
    orow[n] = o;
    out[(size_t)b * (DSTEPS * N_NODES) + s * N_NODES + n] = o;
  }
  __syncthreads();
  for (int n = t; n < N_NODES; n += 256) {
    int e1 = rowptr[n + 1];
    float a = 0.f;
    for (int e = rowptr[n]; e < e1; ++e) a += nrm[e] * orow[col[e]];
    sbuf[b * N_NODES + n] = a;
  }
}

// ---------------- initial decoder aggregation ----------------
__global__ __launch_bounds__(256) void k_agg0(
    const float* __restrict__ dec0, const int* __restrict__ rowptr,
    const int* __restrict__ col, const float* __restrict__ nrm, float* __restrict__ sbuf) {
  __shared__ float irow[N_NODES];
  int b = blockIdx.x, t = threadIdx.x;
  for (int n = t; n < N_NODES; n += 256) irow[n] = dec0[b * N_NODES + n];
  __syncthreads();
  for (int n = t; n < N_NODES; n += 256) {
    int e1 = rowptr[n + 1];
    float a = 0.f;
    for (int e = rowptr[n]; e < e1; ++e) a += nrm[e] * irow[col[e]];
    sbuf[b * N_NODES + n] = a;
  }
}

extern "C" void kernel_launch(void* const* d_in, const int* in_sizes, int n_in,
                              void* d_out, int out_size, void* d_ws, size_t ws_size,
                              hipStream_t stream) {
  const float* x = (const float*)d_in[0];
  const float* dec0 = (const float*)d_in[1];
  const int* ei = (const int*)d_in[2];
  const float* gWe = (const float*)d_in[3];
  const float* gbe = (const float*)d_in[4];
  const float* gWd = (const float*)d_in[5];
  const float* gbd = (const float*)d_in[6];
  const float* eWih = (const float*)d_in[7];
  const float* eWhh = (const float*)d_in[8];
  const float* ebih = (const float*)d_in[9];
  const float* ebhh = (const float*)d_in[10];
  const float* dWih = (const float*)d_in[11];
  const float* dWhh = (const float*)d_in[12];
  const float* dbih = (const float*)d_in[13];
  const float* dbhh = (const float*)d_in[14];
  const float* fcW = (const float*)d_in[15];
  const float* fcb = (const float*)d_in[16];
  float* out = (float*)d_out;
  (void)in_sizes; (void)n_in; (void)out_size; (void)ws_size;

  char* w = (char*)d_ws;
  size_t off = 0;
  auto alloc = [&](size_t bytes) -> void* {
    void* p = w + off;
    off = (off + bytes + 255) & ~(size_t)255;
    return p;
  };
  int* deg = (int*)alloc(512 * 4);
  float* dinv = (float*)alloc(512 * 4);
  int* rowptr = (int*)alloc(512 * 4);
  int* cursor = (int*)alloc(512 * 4);
  int* colA = (int*)alloc(E_TOT * 4);
  float* nrmA = (float*)alloc(E_TOT * 4);
  unsigned short* whhE = (unsigned short*)alloc((size_t)G3 * DH * 2);
  unsigned short* whhD = (unsigned short*)alloc((size_t)G3 * DH * 2);
  unsigned short* AhatD = (unsigned short*)alloc(512 * 512 * 2);
  float* hF = (float*)alloc(NB * DH * 4);                     // | contiguous:
  unsigned short* hbX = (unsigned short*)alloc(NB * DH * 2);  // | one memset
  int* arr = (int*)alloc(256);                                // |
  unsigned short* hbY = (unsigned short*)alloc(NB * DH * 2);
  float* sbuf = (float*)alloc((size_t)NB * N_NODES * 4);
  unsigned short* emb = (unsigned short*)alloc((size_t)BT * NH * 2);
  char* wihE_parts = (char*)alloc((size_t)G3 * NH * 2);   // wihE, later parts
  unsigned short* wihE = (unsigned short*)wihE_parts;
  float* parts = (float*)wihE_parts;
  unsigned short* wihD = (unsigned short*)alloc((size_t)G3 * NH * 2);
  char* xT2_giP = (char*)alloc((size_t)16384 * 512 * 2);  // xT2, later giP2
  unsigned short* xT2 = (unsigned short*)xT2_giP;
  float* giP2 = (float*)xT2_giP;

  // zero hF + hbX + arr (contiguous region)
  hipMemsetAsync(hF, 0, NB * DH * 4 + NB * DH * 2 + 256, stream);

  k_deg_init<<<2, 256, 0, stream>>>(deg);
  k_deg_count<<<(E_EDGES + 255) / 256, 256, 0, stream>>>(ei, deg);
  k_scan<<<1, 512, 0, stream>>>(deg, dinv, rowptr, cursor);
  k_scatter<<<(E_TOT + 255) / 256, 256, 0, stream>>>(ei, dinv, cursor, colA, nrmA);

  int n4w = G3 * NH / 4;
  int n4h = G3 * DH / 4;
  k_f2bf4<<<(n4w + 255) / 256, 256, 0, stream>>>(eWih, wihE, n4w);
  k_f2bf4<<<(n4w + 255) / 256, 256, 0, stream>>>(dWih, wihD, n4w);
  k_f2bf4<<<(n4h + 255) / 256, 256, 0, stream>>>(eWhh, whhE, n4h);
  k_f2bf4<<<(n4h + 255) / 256, 256, 0, stream>>>(dWhh, whhD, n4h);

  k_transpose<<<BT, 256, 0, stream>>>(x, xT2);
  k_densify<<<512, 256, 0, stream>>>(rowptr, colA, nrmA, AhatD);
  k_gemm_agg<<<dim3(128, 4), 256, 0, stream>>>(xT2, AhatD, gWe, gbe, emb);

  k_gemm_enc<<<dim3(BT / 128, G3 / 64), 256, 0, stream>>>(emb, wihE, giP2);

  k_enc_scan<<<16, 256, 0, stream>>>(whhE, giP2, ebih, ebhh, hF, hbX, hbY, arr);

  k_agg0<<<NB, 256, 0, stream>>>(dec0, rowptr, colA, nrmA, sbuf);

  for (int s = 0; s < DSTEPS; ++s) {
    const unsigned short* hbin = (s & 1) ? hbY : hbX;
    unsigned short* hbout = (s & 1) ? hbX : hbY;
    k_dec_gemm<<<dim3(12, 20), 256, 0, stream>>>(wihD, sbuf, gWd, gbd, parts);
    k_gru_dec<<<16, 256, 0, stream>>>(whhD, parts, dbih, dbhh, hF, hbin, hbout);
    k_fc_agg<<<NB, 256, 0, stream>>>(hF, fcW, fcb, rowptr, colA, nrmA, out, sbuf, s);
  }
}